// Round 2
// baseline (230.866 us; speedup 1.0000x reference)
//
#include <hip/hip_runtime.h>
#include <cfloat>

#pragma clang fp contract(off)

#define NCLS 80
#define PDIM 85
#define NA   8400
#define NAP  8448          // padded per-image anchor stride = 33*256 (BPI*64)
#define NB   16
#define NT   128
#define NTOP 10
#define APB  64      // anchors per k0 block
#define BPI  132     // ceil(NA/64) ; BPI*64 == NAP
#define BPI2 33      // k2: 256 anchors per block ; BPI2*256 == NAP
#define LN2  0.6931471805599453f
#define CAPW 768     // per-wave compaction capacity (int entries; worst case ~300)

#define BAPC ((size_t)NB*NAP)

#define KSENT 0xFFFFFFFF7FFFFFFFull   // sentinel key: huge cost, idx 0x7FFFFFFF

// fast native sigmoid: rcp(1+exp(-x)).
__device__ __forceinline__ float sigm_fast(float x){
  float e = __expf(-x);
  return __builtin_amdgcn_rcpf(1.0f + e);
}

// fast bce (value path only)
__device__ __forceinline__ float bce_fast(float x, float t){
  float ax = fabsf(x);
  float e  = __expf(-ax);
  return fmaxf(x,0.0f) - x*t + LN2*__builtin_amdgcn_logf(1.0f + e);
}

// Fast-rcp IoU. Used identically in k1 phase-2 and k2 -> internally consistent.
__device__ __forceinline__ float pair_iou(float tx1,float ty1,float tx2,float ty2,
                                          float px1,float py1,float px2,float py2){
  float w = fminf(tx2,px2) - fmaxf(tx1,px1);
  float h = fminf(ty2,py2) - fmaxf(ty1,py1);
  w = fmaxf(w,0.0f); h = fmaxf(h,0.0f);
  float inter = w*h;
  float at = fmaxf(tx2-tx1,0.0f)*fmaxf(ty2-ty1,0.0f);
  float ap = fmaxf(px2-px1,0.0f)*fmaxf(py2-py1,0.0f);
  float den = at+ap-inter+1e-8f;
  return inter * __builtin_amdgcn_rcpf(den);
}

// dval fallback (use_d==0 only; normally D table is used)
__device__ __forceinline__ float dval_fn(float sobj, float lg){
  float ln_sobj = LN2*__builtin_amdgcn_logf(sobj);
  float e = __expf(-fabsf(lg));
  float L = LN2*__builtin_amdgcn_logf(1.0f + e);
  float ln_sc = -(fmaxf(-lg,0.0f) + L);
  float lph = 0.5f*(ln_sobj + ln_sc);
  float p = __expf(lph);
  float lp = fmaxf(lph, -100.0f);
  float l1 = fmaxf(LN2*__builtin_amdgcn_logf(fmaxf(1.0f - p, 0.0f)), -100.0f);
  return lp - l1;
}

// Selection-critical: identical in k1 top-k and k2 argmin (same inline, contract off).
__device__ __forceinline__ float cost_from(float S, float dval, float iou, bool ibc, bool ib){
  float iouc = -LN2 * __builtin_amdgcn_logf(iou + 1e-8f);
  float clsc = -(S + dval);
  float c = clsc + 3.0f*iouc;
  c = c + (ibc ? 0.0f : 100000.0f);
  c = c + (ib  ? 0.0f : 1000000000.0f);
  return c;
}

// sortable u64 key: ascending key order == ascending (cost, idx) lexicographic
__device__ __forceinline__ unsigned long long key_of(float c, int idx){
  unsigned int u = __float_as_uint(c);
  u ^= (u & 0x80000000u) ? 0xFFFFFFFFu : 0x80000000u;
  return ((unsigned long long)u << 32) | (unsigned int)idx;
}

// sorted-insert helpers (branchless unrolled shift; order-independent)
__device__ __forceinline__ void ins_iou(float* riou, float iou){
  if (iou > riou[NTOP-1]){
    #pragma unroll
    for (int j = NTOP-1; j >= 1; --j){
      bool gj  = iou > riou[j];
      bool gj1 = iou > riou[j-1];
      riou[j] = gj ? (gj1 ? riou[j-1] : iou) : riou[j];
    }
    riou[0] = (iou > riou[0]) ? iou : riou[0];
  }
}
__device__ __forceinline__ void ins_key(unsigned long long* rk, unsigned long long key){
  if (key < rk[NTOP-1]){
    #pragma unroll
    for (int j = NTOP-1; j >= 1; --j){
      bool bj  = key < rk[j];
      bool bj1 = key < rk[j-1];
      rk[j] = bj ? (bj1 ? rk[j-1] : key) : rk[j];
    }
    rk[0] = (key < rk[0]) ? key : rk[0];
  }
}

// ---------------- Kernel 0: transpose + per-anchor precompute ----------------
__global__ __launch_bounds__(256) void k0_precompute(
    const float* __restrict__ pred, const float* __restrict__ target,
    const float* __restrict__ grid, const float* __restrict__ stridev,
    float4* __restrict__ pbox4, float4* __restrict__ meta4,
    float* __restrict__ obja, float* __restrict__ sobja,
    float* __restrict__ S0a, float* __restrict__ D, int use_d,
    unsigned long long* __restrict__ mask, float* __restrict__ acc)
{
  __shared__ float  tile[APB*PDIM];   // [a][c], stride 85 (odd -> conflict-free)
  __shared__ float4 tb4s[NT];
  __shared__ float  ps_s[4][APB];
  __shared__ float  ps0_s[4][APB];
  __shared__ int    ib_s[4][APB];

  int i  = blockIdx.x / BPI;
  int b  = blockIdx.x % BPI;
  int c0 = b*APB;
  int n  = NA - c0; if (n > APB) n = APB;
  int tid = threadIdx.x;

  if (blockIdx.x == 0) acc[tid] = 0.0f;   // 256 slots

  const float* src = pred + ((size_t)i*NA + c0)*PDIM;
  int tot = n*PDIM;
  for (int idx = tid; idx < tot; idx += 256) tile[idx] = src[idx];
  for (int idx = tid; idx < NT; idx += 256){
    const float* tg = target + (i*NT + idx)*6;
    tb4s[idx] = make_float4(tg[2],tg[3],tg[4],tg[5]);
  }
  __syncthreads();

  int al = tid & 63, cg = tid >> 6;
  if (al < n){
    int gid = i*NAP + c0 + al;
    // softplus identity: ln sigm(x) = -(max(-x,0)+L), L = ln(1+exp(-|x|))
    float x4 = tile[al*PDIM+4];
    float e4 = __expf(-fabsf(x4));
    float L4 = LN2*__builtin_amdgcn_logf(1.0f + e4);
    float ln_sobj = -(fmaxf(-x4,0.0f) + L4);
    float ps = 0.0f, ps0 = 0.0f;
    #pragma unroll 4
    for (int k = 0; k < 20; ++k){
      int c = cg*20 + k;
      float x  = tile[al*PDIM+5+c];
      float e  = __expf(-fabsf(x));
      float L  = LN2*__builtin_amdgcn_logf(1.0f + e);
      float ln_sc = -(fmaxf(-x,0.0f) + L);
      float lph = 0.5f*(ln_sobj + ln_sc);     // ln p = 0.5 ln(sobj*sc)
      float p   = __expf(lph);
      float lp  = fmaxf(lph, -100.0f);
      float l1  = fmaxf(LN2*__builtin_amdgcn_logf(fmaxf(1.0f - p, 0.0f)), -100.0f);
      ps  += l1;
      if (use_d) D[(size_t)c*BAPC + gid] = lp - l1;
      ps0 += fmaxf(x,0.0f) + L;               // bce(x,0) reuses L
    }
    ps_s[cg][al] = ps; ps0_s[cg][al] = ps0;

    int ga = c0 + al;
    float xg = grid[2*ga], yg = grid[2*ga+1], sv = stridev[ga];
    float xc = (xg + 0.5f)*sv, yc = (yg + 0.5f)*sv;
    float rc = 2.5f*sv;
    bool ibp = false;
    #pragma unroll 4
    for (int t = cg*32; t < cg*32+32; ++t){
      float4 T = tb4s[t];
      bool inb = (xc-T.x>0.0f)&&(yc-T.y>0.0f)&&(T.z-xc>0.0f)&&(T.w-yc>0.0f);
      float txc=(T.x+T.z)*0.5f, tyc=(T.y+T.w)*0.5f;
      bool inc = fmaxf(fabsf(xc-txc),fabsf(yc-tyc)) < rc;
      ibp = ibp || inb || inc;
    }
    ib_s[cg][al] = ibp ? 1 : 0;
  }
  __syncthreads();

  if (tid < n){
    int a = tid;
    int gid = i*NAP + c0 + a;
    float s  = ps_s[0][a]  + ps_s[1][a]  + ps_s[2][a]  + ps_s[3][a];
    float s0 = ps0_s[0][a] + ps0_s[1][a] + ps0_s[2][a] + ps0_s[3][a];
    bool ib  = (ib_s[0][a] | ib_s[1][a] | ib_s[2][a] | ib_s[3][a]) != 0;

    float x1 = tile[a*PDIM+0], y1 = tile[a*PDIM+1];
    float x2 = tile[a*PDIM+2], y2 = tile[a*PDIM+3];
    float ol = tile[a*PDIM+4];
    pbox4[gid] = make_float4(x1,y1,x2,y2);
    obja[gid]  = ol;
    sobja[gid] = sigm_fast(ol);
    S0a[gid]   = s0;
    mask[(size_t)gid*2]   = 0ull;   // replaces host-side memset
    mask[(size_t)gid*2+1] = 0ull;

    int ga = c0 + a;
    float xg = grid[2*ga], yg = grid[2*ga+1], sv = stridev[ga];
    float xc = (xg + 0.5f)*sv, yc = (yg + 0.5f)*sv;
    float rc = 2.5f*sv;
    meta4[gid] = make_float4(xc, yc, ib ? rc : -rc, s);  // sign(z) = in_box
  } else if (tid < APB){
    // pad anchors (only last block per image, n=16): never active in k1/k2
    int gid = i*NAP + c0 + tid;
    meta4[gid] = make_float4(0.0f, 0.0f, -1.0f, 0.0f);
    pbox4[gid] = make_float4(0.0f, 0.0f, 0.0f, 0.0f);
  }
}

// ---- Kernel 1: per-target compact scan + register tournament top-k ----------
// Phase 1 is a cheap candidacy test only (7-op overlap == iou>0 exactly);
// full IoU/cost deferred to phase-2 over the ~2-4% candidates.
__global__ __launch_bounds__(256) void k1_pertarget(
    const float4* __restrict__ pbox4, const float4* __restrict__ meta4,
    const float* __restrict__ D, int use_d,
    const float* __restrict__ sobja, const float* __restrict__ pred,
    const float* __restrict__ target,
    float* __restrict__ rowmax, unsigned long long* __restrict__ mask)
{
  __shared__ int   seg[4*CAPW];                      // 12 KB (index | ibc<<15)
  __shared__ int   cnts_s[4], cibc_s[4];
  __shared__ float wiou[4][NTOP];                    // per-wave desc iou
  __shared__ unsigned long long wkey[4][NTOP];       // per-wave asc cost keys

  int tid = threadIdx.x, lane = tid & 63, w = tid >> 6;
  int g = blockIdx.x;
  int i = g / NT, t = g - i*NT;
  int iNAP = i*NAP;
  int iNA  = i*NA;
  const float* m4f = (const float*)meta4;

  const float* tg = target + (size_t)g*6;
  int   cid = (int)tg[1];
  float tx1 = tg[2], ty1 = tg[3], tx2 = tg[4], ty2 = tg[5];
  float txc = (tx1+tx2)*0.5f, tyc = (ty1+ty2)*0.5f;
  const float* Dc = use_d ? (D + (size_t)cid*BAPC) : nullptr;

  // ---- phase 1: prefetched cheap scan, per-wave compaction (no IoU) ----
  int cnt = 0, ci = 0;
  int a = w*64 + lane;
  float4 pb = pbox4[iNAP+a];
  float4 mt = meta4[iNAP+a];
  for (int k = 0; k < 33; ++k){
    int a2 = a + 256;
    int ld = (a2 < NAP) ? a2 : 0;      // last prefetch discarded
    float4 pbn = pbox4[iNAP+ld];
    float4 mtn = meta4[iNAP+ld];

    bool act = (mt.z > 0.0f);          // in_box-any; pads have z=-1
    // strict overlap == (iou > 0): inter>0 iff both extents positive
    bool ov  = (fminf(tx2,pb.z) > fmaxf(tx1,pb.x)) &&
               (fminf(ty2,pb.w) > fmaxf(ty1,pb.y));
    bool inb = (mt.x-tx1>0.0f)&&(mt.y-ty1>0.0f)&&(tx2-mt.x>0.0f)&&(ty2-mt.y>0.0f);
    bool inc = fmaxf(fabsf(mt.x-txc),fabsf(mt.y-tyc)) < mt.z;
    bool ibc = inb && inc;             // ibc => inb => act (for real anchors)
    bool cand = act && (ov || ibc);
    unsigned long long bb  = __ballot(cand);
    unsigned long long bb2 = __ballot(ibc);
    if (cand){
      int pos = cnt + __popcll(bb & ((1ull << lane) - 1ull));
      if (pos < CAPW) seg[w*CAPW + pos] = a | (ibc ? (1<<15) : 0);
    }
    cnt += __popcll(bb);
    ci  += __popcll(bb2);
    pb = pbn; mt = mtn; a = a2;
  }
  if (lane == 0){ cnts_s[w] = cnt; cibc_s[w] = ci; }
  __syncthreads();

  int tibc = cibc_s[0]+cibc_s[1]+cibc_s[2]+cibc_s[3];
  bool ovf = (cnts_s[0]>CAPW)||(cnts_s[1]>CAPW)||(cnts_s[2]>CAPW)||(cnts_s[3]>CAPW);
  bool fastp = !ovf && (tibc >= 16);

  float riou[NTOP]; unsigned long long rk[NTOP];
  #pragma unroll
  for (int j=0;j<NTOP;++j){ riou[j]=0.0f; rk[j]=KSENT; }

  if (fastp){
    int cw = cnts_s[w];
    for (int j = lane; j < cw; j += 64){
      int e  = seg[w*CAPW + j];
      int a1 = e & 0x3fff;
      bool ibc = (e & (1<<15)) != 0;
      int gid = iNAP + a1;
      float4 pb2 = pbox4[gid];                      // L2-hot gather
      float iou = pair_iou(tx1,ty1,tx2,ty2, pb2.x,pb2.y,pb2.z,pb2.w);
      ins_iou(riou, iou);
      float S  = m4f[(size_t)gid*4 + 3];
      float dv = use_d ? Dc[gid] : dval_fn(sobja[gid], pred[(size_t)(iNA+a1)*PDIM + 5 + cid]);
      float c  = cost_from(S, dv, iou, ibc, true);
      ins_key(rk, key_of(c, a1));
    }
  } else {
    // exact fallback: full rescan by all 256 threads (rare)
    for (int a1 = tid; a1 < NA; a1 += 256){
      float4 mt2 = meta4[iNAP+a1];
      if (mt2.z > 0.0f){
        float4 pb2 = pbox4[iNAP+a1];
        float iou = pair_iou(tx1,ty1,tx2,ty2, pb2.x,pb2.y,pb2.z,pb2.w);
        ins_iou(riou, iou);
        bool inb = (mt2.x-tx1>0.0f)&&(mt2.y-ty1>0.0f)&&(tx2-mt2.x>0.0f)&&(ty2-mt2.y>0.0f);
        bool inc = fmaxf(fabsf(mt2.x-txc),fabsf(mt2.y-tyc)) < mt2.z;
        float dv = use_d ? Dc[iNAP+a1] : dval_fn(sobja[iNAP+a1], pred[(size_t)(iNA+a1)*PDIM + 5 + cid]);
        float c = cost_from(mt2.w, dv, iou, inb&&inc, true);
        ins_key(rk, key_of(c, a1));
      }
    }
  }

  // ---- per-wave tournament pop: 10 rounds wave-reduce + winner-pop ----
  #pragma unroll
  for (int r = 0; r < NTOP; ++r){
    float gm = riou[0];
    #pragma unroll
    for (int m = 1; m < 64; m <<= 1) gm = fmaxf(gm, __shfl_xor(gm, m));
    unsigned long long bb = __ballot(riou[0] == gm);
    int win = __ffsll(bb) - 1;
    if (lane == win){
      #pragma unroll
      for (int j=0;j<NTOP-1;++j) riou[j] = riou[j+1];
      riou[NTOP-1] = 0.0f;
    }
    if (lane == 0) wiou[w][r] = gm;
  }
  #pragma unroll
  for (int r = 0; r < NTOP; ++r){
    unsigned long long gk = rk[0];
    #pragma unroll
    for (int m = 1; m < 64; m <<= 1){
      unsigned long long o = __shfl_xor(gk, m);
      gk = (o < gk) ? o : gk;
    }
    unsigned long long bb = __ballot(rk[0] == gk);
    int win = __ffsll(bb) - 1;
    if (lane == win){
      #pragma unroll
      for (int j=0;j<NTOP-1;++j) rk[j] = rk[j+1];
      rk[NTOP-1] = KSENT;
    }
    if (lane == 0) wkey[w][r] = gk;
  }
  __syncthreads();

  // ---- wave 0: 4-way pointer merge (global desc iou sum; asc cost keys) ----
  if (w == 0){
    int p0=0,p1=0,p2=0,p3=0;
    float ssum = 0.0f, rmax = 0.0f;
    #pragma unroll
    for (int r = 0; r < NTOP; ++r){
      float v0=wiou[0][p0], v1=wiou[1][p1], v2=wiou[2][p2], v3=wiou[3][p3];
      float mx = fmaxf(fmaxf(v0,v1), fmaxf(v2,v3));
      if (r == 0) rmax = mx;
      ssum += mx;                                   // global desc order, like jnp
      if      (mx == v0) ++p0;
      else if (mx == v1) ++p1;
      else if (mx == v2) ++p2;
      else               ++p3;
    }
    int dk = (int)ssum;
    if (dk < 1) dk = 1;

    int q0=0,q1=0,q2=0,q3=0;
    int myidx = 0x7fffffff;
    #pragma unroll
    for (int r = 0; r < NTOP; ++r){
      unsigned long long k0=wkey[0][q0], k1=wkey[1][q1], k2=wkey[2][q2], k3=wkey[3][q3];
      unsigned long long mn = k0;
      mn = (k1 < mn) ? k1 : mn;
      mn = (k2 < mn) ? k2 : mn;
      mn = (k3 < mn) ? k3 : mn;
      if (lane == r) myidx = (int)(mn & 0xFFFFFFFFull);
      if      (mn == k0) ++q0;
      else if (mn == k1) ++q1;
      else if (mn == k2) ++q2;
      else               ++q3;
    }

    if (lane == 0) rowmax[g] = rmax;
    if (lane < NTOP && lane < dk){
      int a1 = myidx;
      if (a1 >= 0 && a1 < NA){     // sentinel idx = 0x7FFFFFFF skipped
        atomicOr(&mask[(size_t)(iNAP + a1)*2 + (t>>6)], 1ull << (t & 63));
      }
    }
  }
}

// ---------- Kernel 2: per-anchor resolution + loss partial sums --------------
// One thread = one anchor; full 128-target loop per thread (LDS broadcast).
// 4x fewer blocks than before, no cross-segment LDS reduces, one sync.
__global__ __launch_bounds__(256) void k2_peranchor(
    const float* __restrict__ pred,
    const float4* __restrict__ pbox4, const float4* __restrict__ meta4,
    const float* __restrict__ obja, const float* __restrict__ sobja,
    const float* __restrict__ S0a,
    const float* __restrict__ D, int use_d,
    const float* __restrict__ target,
    const float* __restrict__ rowmax, const unsigned long long* __restrict__ mask,
    float* __restrict__ acc)
{
  __shared__ float4 tb4[NT];
  __shared__ int    tcid[NT];
  __shared__ float  invm[NT];
  __shared__ float  tarea[NT];

  int i  = blockIdx.x / BPI2;
  int b  = blockIdx.x - i*BPI2;
  int a  = b*256 + threadIdx.x;        // 0..NAP-1
  int gid = i*NAP + a;

  if (threadIdx.x < NT){
    int idx = threadIdx.x;
    const float* tg = target + (i*NT + idx)*6;
    tcid[idx] = (int)tg[1];
    float x1=tg[2], y1=tg[3], x2=tg[4], y2=tg[5];
    tb4[idx]   = make_float4(x1,y1,x2,y2);
    invm[idx]  = 1.0f / (rowmax[i*NT + idx] + 1e-8f);
    tarea[idx] = fmaxf(x2-x1,0.0f)*fmaxf(y2-y1,0.0f);
  }
  __syncthreads();

  bool valid = (a < NA);
  float4 pb = pbox4[gid];              // pads: zero box (k0-initialized)
  float4 mt = meta4[gid];              // pads: z=-1
  bool ib = valid && (mt.z > 0.0f);
  float rc = fabsf(mt.z);
  float px1=pb.x, py1=pb.y, px2=pb.z, py2=pb.w;
  float ap = fmaxf(px2-px1,0.0f)*fmaxf(py2-py1,0.0f);

  // obj target: max_t iou*invm  (sequential fmax == old segment tree, exact)
  float best = 0.0f;
  if (ib){
    #pragma unroll 4
    for (int t = 0; t < NT; ++t){
      float4 T = tb4[t];
      float w = fminf(T.z,px2) - fmaxf(T.x,px1);
      float h = fminf(T.w,py2) - fmaxf(T.y,py1);
      w = fmaxf(w,0.0f); h = fmaxf(h,0.0f);
      float inter = w*h;
      float den = tarea[t] + ap - inter + 1e-8f;
      float iou = inter * __builtin_amdgcn_rcpf(den);
      best = fmaxf(best, iou*invm[t]);
    }
  }

  unsigned long long m0=0, m1=0;
  if (valid){ m0 = mask[(size_t)gid*2]; m1 = mask[(size_t)gid*2+1]; }
  int cnt = __popcll(m0) + __popcll(m1);

  // conflict resolution: strict < over ascending t == first-min (ref argmin)
  float bc = FLT_MAX; int bt = NT;
  if (cnt > 1){
    float sobj = use_d ? 0.0f : sobja[gid];
    float Sg = mt.w;
    size_t pbase = (size_t)(i*NA + a)*PDIM;
    for (int t = 0; t < NT; ++t){
      float4 T = tb4[t];
      float iou = ib ? pair_iou(T.x,T.y,T.z,T.w,px1,py1,px2,py2) : 0.0f;
      bool inb = (mt.x-T.x>0.0f)&&(mt.y-T.y>0.0f)&&(T.z-mt.x>0.0f)&&(T.w-mt.y>0.0f);
      float txc=(T.x+T.z)*0.5f, tyc=(T.y+T.w)*0.5f;
      bool inc = fmaxf(fabsf(mt.x-txc),fabsf(mt.y-tyc)) < rc;
      float dv = use_d ? D[(size_t)tcid[t]*BAPC + gid]
                       : dval_fn(sobj, pred[pbase + 5 + tcid[t]]);
      float c = cost_from(Sg, dv, iou, inb&&inc, ib);
      if (c < bc){ bc = c; bt = t; }
    }
  }

  float m=0.0f, vbox=0.0f, vobj=0.0f, vcls=0.0f;
  if (valid){
    float obj_t = ib ? fminf(fmaxf(best,0.0f),1.0f) : 0.0f;
    vobj = bce_fast(obja[gid], obj_t);

    int tp = 0; bool mpv = false;
    if (cnt > 1){ tp = bt; mpv = true; }
    else if (cnt == 1){
      tp = m0 ? (__ffsll(m0)-1) : (64 + __ffsll(m1)-1);
      mpv = true;
    }

    if (mpv){
      m = 1.0f;
      float4 T = tb4[tp];
      float x1=T.x, y1=T.y, x2=T.z, y2=T.w;
      float w = fmaxf(fminf(px2,x2)-fmaxf(px1,x1),0.0f);
      float h = fmaxf(fminf(py2,y2)-fmaxf(py1,y1),0.0f);
      float inter = w*h;
      float wp=px2-px1, hp=py2-py1, wt=x2-x1, ht=y2-y1;
      float iou = inter/(wp*hp + wt*ht - inter + 1e-8f);
      float cw = fmaxf(px2,x2)-fminf(px1,x1);
      float ch = fmaxf(py2,y2)-fminf(py1,y1);
      float c2 = cw*cw + ch*ch + 1e-8f;
      float dx = (px1+px2)-(x1+x2), dy = (py1+py2)-(y1+y2);
      float rho2 = (dx*dx + dy*dy)/4.0f;
      float da = atanf(wt/(ht+1e-8f)) - atanf(wp/(hp+1e-8f));
      float v  = 0.4052847345693511f * da * da;   // 4/pi^2
      float alpha = v/(1.0f - iou + v + 1e-8f);
      vbox = 1.0f - (iou - rho2/c2 - alpha*v);

      int cc = tcid[tp];
      float xcc = pred[(size_t)(i*NA + a)*PDIM + 5 + cc];
      vcls = (S0a[gid] - xcc) * (1.0f/80.0f);   // sum_c bce(x_c, onehot) = S0 - x_cc
    }
  }

  // wave-level reduce, one atomic quad per wave
  #pragma unroll
  for (int off=32; off>0; off>>=1){
    m    += __shfl_down(m, off);
    vbox += __shfl_down(vbox, off);
    vobj += __shfl_down(vobj, off);
    vcls += __shfl_down(vcls, off);
  }
  if ((threadIdx.x & 63) == 0){
    int slot = (blockIdx.x & 63)*4;
    atomicAdd(&acc[slot+0], m);
    atomicAdd(&acc[slot+1], vbox);
    atomicAdd(&acc[slot+2], vobj);
    atomicAdd(&acc[slot+3], vcls);
  }
}

// ---------------- Kernel 3: finalize (reduce 64 accumulator slots) -----------
__global__ void k3_final(const float* __restrict__ acc, float* __restrict__ out){
  int l = threadIdx.x;   // 64 threads
  float4 v = ((const float4*)acc)[l];
  #pragma unroll
  for (int off=32; off>0; off>>=1){
    v.x += __shfl_down(v.x, off);
    v.y += __shfl_down(v.y, off);
    v.z += __shfl_down(v.z, off);
    v.w += __shfl_down(v.w, off);
  }
  if (l == 0){
    float n    = fmaxf(v.x, 1.0f);
    float lbox = 0.05f * v.y / n;
    float lobj = v.z / (float)(NB*NA);
    float lcls = 0.5f  * v.w / n;
    out[0] = lbox + lobj + lcls;
    out[1] = lbox; out[2] = lobj; out[3] = lcls;
  }
}

extern "C" void kernel_launch(void* const* d_in, const int* in_sizes, int n_in,
                              void* d_out, int out_size, void* d_ws, size_t ws_size,
                              hipStream_t stream) {
  const float* pred    = (const float*)d_in[0];
  const float* target  = (const float*)d_in[1];
  const float* grid    = (const float*)d_in[2];
  const float* stridev = (const float*)d_in[3];
  float* out = (float*)d_out;

  char* ws = (char*)d_ws;

  size_t off = 0;
  unsigned long long* mask = (unsigned long long*)(ws + off); off += BAPC*16;
  float* acc    = (float*)(ws + off); off += 64*4*4;
  float4* pbox4 = (float4*)(ws + off); off += BAPC*16;
  float4* meta4 = (float4*)(ws + off); off += BAPC*16;
  float* obja   = (float*)(ws + off); off += BAPC*4;
  float* sobja  = (float*)(ws + off); off += BAPC*4;
  float* S0a    = (float*)(ws + off); off += BAPC*4;
  float* rowmax = (float*)(ws + off); off += (size_t)NB*NT*4;
  float* D      = (float*)(ws + off);
  const size_t need_d = off + (size_t)NCLS*BAPC*4;
  int use_d = (ws_size >= need_d) ? 1 : 0;

  // mask+acc zeroed inside k0 (no memset dispatch); separate k3 (the fused
  // finalize's per-block __threadfence cost ~15-30us on 8-XCD L2 -> reverted)
  k0_precompute<<<NB*BPI, 256, 0, stream>>>(pred, target, grid, stridev,
                                            pbox4, meta4, obja, sobja, S0a, D, use_d,
                                            mask, acc);
  k1_pertarget <<<NB*NT,  256, 0, stream>>>(pbox4, meta4, D, use_d,
                                            sobja, pred, target, rowmax, mask);
  k2_peranchor <<<NB*BPI2, 256, 0, stream>>>(pred, pbox4, meta4, obja, sobja, S0a,
                                             D, use_d, target, rowmax, mask, acc);
  k3_final     <<<1, 64, 0, stream>>>(acc, out);
}

// Round 3
// 229.296 us; speedup vs baseline: 1.0068x; 1.0068x over previous
//
#include <hip/hip_runtime.h>
#include <cfloat>

#pragma clang fp contract(off)

#define NCLS 80
#define PDIM 85
#define NA   8400
#define NAP  8448          // padded per-image anchor stride = 33*256 (BPI*64)
#define NB   16
#define NT   128
#define NTOP 10
#define APB  64      // anchors per k0 block
#define BPI  132     // ceil(NA/64) ; BPI*64 == NAP
#define BPI2 33      // k2: 256 anchors per block ; BPI2*256 == NAP
#define LN2  0.6931471805599453f
#define CAPW 768     // per-wave compaction capacity (int entries; worst case ~300)

#define BAPC ((size_t)NB*NAP)

#define KSENT 0xFFFFFFFF7FFFFFFFull   // sentinel key: huge cost, idx 0x7FFFFFFF

// fast native sigmoid: rcp(1+exp(-x)).
__device__ __forceinline__ float sigm_fast(float x){
  float e = __expf(-x);
  return __builtin_amdgcn_rcpf(1.0f + e);
}

// fast bce (value path only)
__device__ __forceinline__ float bce_fast(float x, float t){
  float ax = fabsf(x);
  float e  = __expf(-ax);
  return fmaxf(x,0.0f) - x*t + LN2*__builtin_amdgcn_logf(1.0f + e);
}

// Fast-rcp IoU. Used identically in k1 (topk + obj re-walk) and k2 -> consistent.
__device__ __forceinline__ float pair_iou(float tx1,float ty1,float tx2,float ty2,
                                          float px1,float py1,float px2,float py2){
  float w = fminf(tx2,px2) - fmaxf(tx1,px1);
  float h = fminf(ty2,py2) - fmaxf(ty1,py1);
  w = fmaxf(w,0.0f); h = fmaxf(h,0.0f);
  float inter = w*h;
  float at = fmaxf(tx2-tx1,0.0f)*fmaxf(ty2-ty1,0.0f);
  float ap = fmaxf(px2-px1,0.0f)*fmaxf(py2-py1,0.0f);
  float den = at+ap-inter+1e-8f;
  return inter * __builtin_amdgcn_rcpf(den);
}

// dval fallback (use_d==0 only; normally D table is used)
__device__ __forceinline__ float dval_fn(float sobj, float lg){
  float ln_sobj = LN2*__builtin_amdgcn_logf(sobj);
  float e = __expf(-fabsf(lg));
  float L = LN2*__builtin_amdgcn_logf(1.0f + e);
  float ln_sc = -(fmaxf(-lg,0.0f) + L);
  float lph = 0.5f*(ln_sobj + ln_sc);
  float p = __expf(lph);
  float lp = fmaxf(lph, -100.0f);
  float l1 = fmaxf(LN2*__builtin_amdgcn_logf(fmaxf(1.0f - p, 0.0f)), -100.0f);
  return lp - l1;
}

// Selection-critical: identical in k1 top-k and k2 argmin (same inline, contract off).
__device__ __forceinline__ float cost_from(float S, float dval, float iou, bool ibc, bool ib){
  float iouc = -LN2 * __builtin_amdgcn_logf(iou + 1e-8f);
  float clsc = -(S + dval);
  float c = clsc + 3.0f*iouc;
  c = c + (ibc ? 0.0f : 100000.0f);
  c = c + (ib  ? 0.0f : 1000000000.0f);
  return c;
}

// sortable u64 key: ascending key order == ascending (cost, idx) lexicographic
__device__ __forceinline__ unsigned long long key_of(float c, int idx){
  unsigned int u = __float_as_uint(c);
  u ^= (u & 0x80000000u) ? 0xFFFFFFFFu : 0x80000000u;
  return ((unsigned long long)u << 32) | (unsigned int)idx;
}

// sorted-insert helpers (branchless unrolled shift; order-independent)
__device__ __forceinline__ void ins_iou(float* riou, float iou){
  if (iou > riou[NTOP-1]){
    #pragma unroll
    for (int j = NTOP-1; j >= 1; --j){
      bool gj  = iou > riou[j];
      bool gj1 = iou > riou[j-1];
      riou[j] = gj ? (gj1 ? riou[j-1] : iou) : riou[j];
    }
    riou[0] = (iou > riou[0]) ? iou : riou[0];
  }
}
__device__ __forceinline__ void ins_key(unsigned long long* rk, unsigned long long key){
  if (key < rk[NTOP-1]){
    #pragma unroll
    for (int j = NTOP-1; j >= 1; --j){
      bool bj  = key < rk[j];
      bool bj1 = key < rk[j-1];
      rk[j] = bj ? (bj1 ? rk[j-1] : key) : rk[j];
    }
    rk[0] = (key < rk[0]) ? key : rk[0];
  }
}

// ---------------- Kernel 0: transpose + per-anchor precompute ----------------
__global__ __launch_bounds__(256) void k0_precompute(
    const float* __restrict__ pred, const float* __restrict__ target,
    const float* __restrict__ grid, const float* __restrict__ stridev,
    float4* __restrict__ pbox4, float4* __restrict__ meta4,
    float* __restrict__ obja, float* __restrict__ sobja,
    float* __restrict__ S0a, float* __restrict__ D, int use_d,
    unsigned long long* __restrict__ mask, unsigned int* __restrict__ obju,
    float* __restrict__ acc)
{
  __shared__ float  tile[APB*PDIM];   // [a][c], stride 85 (odd -> conflict-free)
  __shared__ float4 tb4s[NT];
  __shared__ float  ps_s[4][APB];
  __shared__ float  ps0_s[4][APB];
  __shared__ int    ib_s[4][APB];

  int i  = blockIdx.x / BPI;
  int b  = blockIdx.x % BPI;
  int c0 = b*APB;
  int n  = NA - c0; if (n > APB) n = APB;
  int tid = threadIdx.x;

  if (blockIdx.x == 0) acc[tid] = 0.0f;   // 256 slots

  const float* src = pred + ((size_t)i*NA + c0)*PDIM;
  int tot = n*PDIM;
  for (int idx = tid; idx < tot; idx += 256) tile[idx] = src[idx];
  for (int idx = tid; idx < NT; idx += 256){
    const float* tg = target + (i*NT + idx)*6;
    tb4s[idx] = make_float4(tg[2],tg[3],tg[4],tg[5]);
  }
  __syncthreads();

  int al = tid & 63, cg = tid >> 6;
  if (al < n){
    int gid = i*NAP + c0 + al;
    // softplus identity: ln sigm(x) = -(max(-x,0)+L), L = ln(1+exp(-|x|))
    float x4 = tile[al*PDIM+4];
    float e4 = __expf(-fabsf(x4));
    float L4 = LN2*__builtin_amdgcn_logf(1.0f + e4);
    float ln_sobj = -(fmaxf(-x4,0.0f) + L4);
    float ps = 0.0f, ps0 = 0.0f;
    #pragma unroll 4
    for (int k = 0; k < 20; ++k){
      int c = cg*20 + k;
      float x  = tile[al*PDIM+5+c];
      float e  = __expf(-fabsf(x));
      float L  = LN2*__builtin_amdgcn_logf(1.0f + e);
      float ln_sc = -(fmaxf(-x,0.0f) + L);
      float lph = 0.5f*(ln_sobj + ln_sc);     // ln p = 0.5 ln(sobj*sc)
      float p   = __expf(lph);
      float lp  = fmaxf(lph, -100.0f);
      float l1  = fmaxf(LN2*__builtin_amdgcn_logf(fmaxf(1.0f - p, 0.0f)), -100.0f);
      ps  += l1;
      if (use_d) D[(size_t)c*BAPC + gid] = lp - l1;
      ps0 += fmaxf(x,0.0f) + L;               // bce(x,0) reuses L
    }
    ps_s[cg][al] = ps; ps0_s[cg][al] = ps0;

    int ga = c0 + al;
    float xg = grid[2*ga], yg = grid[2*ga+1], sv = stridev[ga];
    float xc = (xg + 0.5f)*sv, yc = (yg + 0.5f)*sv;
    float rc = 2.5f*sv;
    bool ibp = false;
    #pragma unroll 4
    for (int t = cg*32; t < cg*32+32; ++t){
      float4 T = tb4s[t];
      bool inb = (xc-T.x>0.0f)&&(yc-T.y>0.0f)&&(T.z-xc>0.0f)&&(T.w-yc>0.0f);
      float txc=(T.x+T.z)*0.5f, tyc=(T.y+T.w)*0.5f;
      bool inc = fmaxf(fabsf(xc-txc),fabsf(yc-tyc)) < rc;
      ibp = ibp || inb || inc;
    }
    ib_s[cg][al] = ibp ? 1 : 0;
  }
  __syncthreads();

  if (tid < n){
    int a = tid;
    int gid = i*NAP + c0 + a;
    float s  = ps_s[0][a]  + ps_s[1][a]  + ps_s[2][a]  + ps_s[3][a];
    float s0 = ps0_s[0][a] + ps0_s[1][a] + ps0_s[2][a] + ps0_s[3][a];
    bool ib  = (ib_s[0][a] | ib_s[1][a] | ib_s[2][a] | ib_s[3][a]) != 0;

    float x1 = tile[a*PDIM+0], y1 = tile[a*PDIM+1];
    float x2 = tile[a*PDIM+2], y2 = tile[a*PDIM+3];
    float ol = tile[a*PDIM+4];
    pbox4[gid] = make_float4(x1,y1,x2,y2);
    obja[gid]  = ol;
    sobja[gid] = sigm_fast(ol);
    S0a[gid]   = s0;
    mask[(size_t)gid*2]   = 0ull;   // replaces host-side memset
    mask[(size_t)gid*2+1] = 0ull;
    obju[gid] = 0u;                 // obj-target accumulator (f32-as-u32, >=0)

    int ga = c0 + a;
    float xg = grid[2*ga], yg = grid[2*ga+1], sv = stridev[ga];
    float xc = (xg + 0.5f)*sv, yc = (yg + 0.5f)*sv;
    float rc = 2.5f*sv;
    meta4[gid] = make_float4(xc, yc, ib ? rc : -rc, s);  // sign(z) = in_box
  } else if (tid < APB){
    // pad anchors (only last block per image, n=16): never active in k1/k2
    int gid = i*NAP + c0 + tid;
    meta4[gid] = make_float4(0.0f, 0.0f, -1.0f, 0.0f);
    pbox4[gid] = make_float4(0.0f, 0.0f, 0.0f, 0.0f);
    obju[gid]  = 0u;
  }
}

// ---- Kernel 1: per-target compact scan + register tournament top-k ----------
// Phase 1: cheap candidacy test only (7-op overlap == iou>0 exactly).
// Phase 2: full IoU/cost over the ~2-4% candidates.
// Phase 3 (new): after rowmax is known, re-walk candidates and scatter the
// per-anchor obj target max(iou*invm) via atomicMax -- this deletes k2's
// 17.2M-pair obj loop entirely (round-2's 89us hotspot).
__global__ __launch_bounds__(256) void k1_pertarget(
    const float4* __restrict__ pbox4, const float4* __restrict__ meta4,
    const float* __restrict__ D, int use_d,
    const float* __restrict__ sobja, const float* __restrict__ pred,
    const float* __restrict__ target,
    unsigned int* __restrict__ obju, unsigned long long* __restrict__ mask)
{
  __shared__ int   seg[4*CAPW];                      // 12 KB (index | ibc<<15)
  __shared__ int   cnts_s[4], cibc_s[4];
  __shared__ float wiou[4][NTOP];                    // per-wave desc iou
  __shared__ unsigned long long wkey[4][NTOP];       // per-wave asc cost keys
  __shared__ float rmax_s;

  int tid = threadIdx.x, lane = tid & 63, w = tid >> 6;
  int g = blockIdx.x;
  int i = g / NT, t = g - i*NT;
  int iNAP = i*NAP;
  int iNA  = i*NA;
  const float* m4f = (const float*)meta4;

  const float* tg = target + (size_t)g*6;
  int   cid = (int)tg[1];
  float tx1 = tg[2], ty1 = tg[3], tx2 = tg[4], ty2 = tg[5];
  float txc = (tx1+tx2)*0.5f, tyc = (ty1+ty2)*0.5f;
  const float* Dc = use_d ? (D + (size_t)cid*BAPC) : nullptr;

  // ---- phase 1: prefetched cheap scan, per-wave compaction (no IoU) ----
  int cnt = 0, ci = 0;
  int a = w*64 + lane;
  float4 pb = pbox4[iNAP+a];
  float4 mt = meta4[iNAP+a];
  for (int k = 0; k < 33; ++k){
    int a2 = a + 256;
    int ld = (a2 < NAP) ? a2 : 0;      // last prefetch discarded
    float4 pbn = pbox4[iNAP+ld];
    float4 mtn = meta4[iNAP+ld];

    bool act = (mt.z > 0.0f);          // in_box-any; pads have z=-1
    // strict overlap == (iou > 0): inter>0 iff both extents positive
    bool ov  = (fminf(tx2,pb.z) > fmaxf(tx1,pb.x)) &&
               (fminf(ty2,pb.w) > fmaxf(ty1,pb.y));
    bool inb = (mt.x-tx1>0.0f)&&(mt.y-ty1>0.0f)&&(tx2-mt.x>0.0f)&&(ty2-mt.y>0.0f);
    bool inc = fmaxf(fabsf(mt.x-txc),fabsf(mt.y-tyc)) < mt.z;
    bool ibc = inb && inc;             // ibc => inb => act (for real anchors)
    bool cand = act && (ov || ibc);
    unsigned long long bb  = __ballot(cand);
    unsigned long long bb2 = __ballot(ibc);
    if (cand){
      int pos = cnt + __popcll(bb & ((1ull << lane) - 1ull));
      if (pos < CAPW) seg[w*CAPW + pos] = a | (ibc ? (1<<15) : 0);
    }
    cnt += __popcll(bb);
    ci  += __popcll(bb2);
    pb = pbn; mt = mtn; a = a2;
  }
  if (lane == 0){ cnts_s[w] = cnt; cibc_s[w] = ci; }
  __syncthreads();

  int tibc = cibc_s[0]+cibc_s[1]+cibc_s[2]+cibc_s[3];
  bool ovf = (cnts_s[0]>CAPW)||(cnts_s[1]>CAPW)||(cnts_s[2]>CAPW)||(cnts_s[3]>CAPW);
  bool fastp = !ovf && (tibc >= 16);

  float riou[NTOP]; unsigned long long rk[NTOP];
  #pragma unroll
  for (int j=0;j<NTOP;++j){ riou[j]=0.0f; rk[j]=KSENT; }

  int cw = cnts_s[w];
  if (fastp){
    for (int j = lane; j < cw; j += 64){
      int e  = seg[w*CAPW + j];
      int a1 = e & 0x3fff;
      bool ibc = (e & (1<<15)) != 0;
      int gid = iNAP + a1;
      float4 pb2 = pbox4[gid];                      // L2-hot gather
      float iou = pair_iou(tx1,ty1,tx2,ty2, pb2.x,pb2.y,pb2.z,pb2.w);
      ins_iou(riou, iou);
      float S  = m4f[(size_t)gid*4 + 3];
      float dv = use_d ? Dc[gid] : dval_fn(sobja[gid], pred[(size_t)(iNA+a1)*PDIM + 5 + cid]);
      float c  = cost_from(S, dv, iou, ibc, true);
      ins_key(rk, key_of(c, a1));
    }
  } else {
    // exact fallback: full rescan by all 256 threads (rare)
    for (int a1 = tid; a1 < NA; a1 += 256){
      float4 mt2 = meta4[iNAP+a1];
      if (mt2.z > 0.0f){
        float4 pb2 = pbox4[iNAP+a1];
        float iou = pair_iou(tx1,ty1,tx2,ty2, pb2.x,pb2.y,pb2.z,pb2.w);
        ins_iou(riou, iou);
        bool inb = (mt2.x-tx1>0.0f)&&(mt2.y-ty1>0.0f)&&(tx2-mt2.x>0.0f)&&(ty2-mt2.y>0.0f);
        bool inc = fmaxf(fabsf(mt2.x-txc),fmaxf(fabsf(mt2.y-tyc),0.0f)) < mt2.z;
        float dv = use_d ? Dc[iNAP+a1] : dval_fn(sobja[iNAP+a1], pred[(size_t)(iNA+a1)*PDIM + 5 + cid]);
        float c = cost_from(mt2.w, dv, iou, inb&&inc, true);
        ins_key(rk, key_of(c, a1));
      }
    }
  }

  // ---- per-wave tournament pop: 10 rounds wave-reduce + winner-pop ----
  #pragma unroll
  for (int r = 0; r < NTOP; ++r){
    float gm = riou[0];
    #pragma unroll
    for (int m = 1; m < 64; m <<= 1) gm = fmaxf(gm, __shfl_xor(gm, m));
    unsigned long long bb = __ballot(riou[0] == gm);
    int win = __ffsll(bb) - 1;
    if (lane == win){
      #pragma unroll
      for (int j=0;j<NTOP-1;++j) riou[j] = riou[j+1];
      riou[NTOP-1] = 0.0f;
    }
    if (lane == 0) wiou[w][r] = gm;
  }
  #pragma unroll
  for (int r = 0; r < NTOP; ++r){
    unsigned long long gk = rk[0];
    #pragma unroll
    for (int m = 1; m < 64; m <<= 1){
      unsigned long long o = __shfl_xor(gk, m);
      gk = (o < gk) ? o : gk;
    }
    unsigned long long bb = __ballot(rk[0] == gk);
    int win = __ffsll(bb) - 1;
    if (lane == win){
      #pragma unroll
      for (int j=0;j<NTOP-1;++j) rk[j] = rk[j+1];
      rk[NTOP-1] = KSENT;
    }
    if (lane == 0) wkey[w][r] = gk;
  }
  __syncthreads();

  // ---- wave 0: 4-way pointer merge for iou (global desc order, like jnp) ----
  int dk = 1;
  if (w == 0){
    int p0=0,p1=0,p2=0,p3=0;
    float ssum = 0.0f, rmax = 0.0f;
    #pragma unroll
    for (int r = 0; r < NTOP; ++r){
      float v0=wiou[0][p0], v1=wiou[1][p1], v2=wiou[2][p2], v3=wiou[3][p3];
      float mx = fmaxf(fmaxf(v0,v1), fmaxf(v2,v3));
      if (r == 0) rmax = mx;
      ssum += mx;
      if      (mx == v0) ++p0;
      else if (mx == v1) ++p1;
      else if (mx == v2) ++p2;
      else               ++p3;
    }
    dk = (int)ssum;
    if (dk < 1) dk = 1;
    if (lane == 0) rmax_s = rmax;
  }
  __syncthreads();

  // ---- phase 3: obj-target scatter over candidates (all 4 waves) ----
  // Bitwise-identical to old k2 obj loop: same pair_iou, same 1/(rmax+1e-8)
  // divide, fmax/atomicMax over nonneg floats (uint order == float order).
  float invm = 1.0f / (rmax_s + 1e-8f);
  if (fastp){
    for (int j = lane; j < cw; j += 64){
      int a1 = seg[w*CAPW + j] & 0x3fff;
      int gid = iNAP + a1;
      float4 pb2 = pbox4[gid];
      float iou = pair_iou(tx1,ty1,tx2,ty2, pb2.x,pb2.y,pb2.z,pb2.w);
      float v = iou * invm;
      if (v > 0.0f) atomicMax(&obju[gid], __float_as_uint(v));
    }
  } else {
    for (int a1 = tid; a1 < NA; a1 += 256){
      float4 mt2 = meta4[iNAP+a1];
      if (mt2.z > 0.0f){
        float4 pb2 = pbox4[iNAP+a1];
        float iou = pair_iou(tx1,ty1,tx2,ty2, pb2.x,pb2.y,pb2.z,pb2.w);
        float v = iou * invm;
        if (v > 0.0f) atomicMax(&obju[iNAP+a1], __float_as_uint(v));
      }
    }
  }

  // ---- wave 0: 4-way pointer merge for cost keys + mask scatter ----
  if (w == 0){
    int q0=0,q1=0,q2=0,q3=0;
    int myidx = 0x7fffffff;
    #pragma unroll
    for (int r = 0; r < NTOP; ++r){
      unsigned long long k0=wkey[0][q0], k1=wkey[1][q1], k2=wkey[2][q2], k3=wkey[3][q3];
      unsigned long long mn = k0;
      mn = (k1 < mn) ? k1 : mn;
      mn = (k2 < mn) ? k2 : mn;
      mn = (k3 < mn) ? k3 : mn;
      if (lane == r) myidx = (int)(mn & 0xFFFFFFFFull);
      if      (mn == k0) ++q0;
      else if (mn == k1) ++q1;
      else if (mn == k2) ++q2;
      else               ++q3;
    }

    if (lane < NTOP && lane < dk){
      int a1 = myidx;
      if (a1 >= 0 && a1 < NA){     // sentinel idx = 0x7FFFFFFF skipped
        atomicOr(&mask[(size_t)(iNAP + a1)*2 + (t>>6)], 1ull << (t & 63));
      }
    }
  }
}

// ---------- Kernel 2: per-anchor resolution + loss partial sums --------------
// obj target now read from obju (computed in k1 over candidates only);
// all-pairs obj loop deleted. Remaining heavy path (cnt>1) is rare.
__global__ __launch_bounds__(256) void k2_peranchor(
    const float* __restrict__ pred,
    const float4* __restrict__ pbox4, const float4* __restrict__ meta4,
    const float* __restrict__ obja, const float* __restrict__ sobja,
    const float* __restrict__ S0a,
    const float* __restrict__ D, int use_d,
    const float* __restrict__ target,
    const unsigned int* __restrict__ obju, const unsigned long long* __restrict__ mask,
    float* __restrict__ acc)
{
  __shared__ float4 tb4[NT];
  __shared__ int    tcid[NT];

  int i  = blockIdx.x / BPI2;
  int b  = blockIdx.x - i*BPI2;
  int a  = b*256 + threadIdx.x;        // 0..NAP-1
  int gid = i*NAP + a;

  if (threadIdx.x < NT){
    int idx = threadIdx.x;
    const float* tg = target + (i*NT + idx)*6;
    tcid[idx] = (int)tg[1];
    tb4[idx]  = make_float4(tg[2],tg[3],tg[4],tg[5]);
  }
  __syncthreads();

  bool valid = (a < NA);
  float4 pb = pbox4[gid];              // pads: zero box (k0-initialized)
  float4 mt = meta4[gid];              // pads: z=-1
  bool ib = valid && (mt.z > 0.0f);
  float rc = fabsf(mt.z);
  float px1=pb.x, py1=pb.y, px2=pb.z, py2=pb.w;

  unsigned long long m0=0, m1=0;
  if (valid){ m0 = mask[(size_t)gid*2]; m1 = mask[(size_t)gid*2+1]; }
  int cnt = __popcll(m0) + __popcll(m1);

  // conflict resolution: strict < over ascending t == first-min (ref argmin)
  float bc = FLT_MAX; int bt = NT;
  if (cnt > 1){
    float sobj = use_d ? 0.0f : sobja[gid];
    float Sg = mt.w;
    size_t pbase = (size_t)(i*NA + a)*PDIM;
    for (int t = 0; t < NT; ++t){
      float4 T = tb4[t];
      float iou = ib ? pair_iou(T.x,T.y,T.z,T.w,px1,py1,px2,py2) : 0.0f;
      bool inb = (mt.x-T.x>0.0f)&&(mt.y-T.y>0.0f)&&(T.z-mt.x>0.0f)&&(T.w-mt.y>0.0f);
      float txc=(T.x+T.z)*0.5f, tyc=(T.y+T.w)*0.5f;
      bool inc = fmaxf(fabsf(mt.x-txc),fabsf(mt.y-tyc)) < rc;
      float dv = use_d ? D[(size_t)tcid[t]*BAPC + gid]
                       : dval_fn(sobj, pred[pbase + 5 + tcid[t]]);
      float c = cost_from(Sg, dv, iou, inb&&inc, ib);
      if (c < bc){ bc = c; bt = t; }
    }
  }

  float m=0.0f, vbox=0.0f, vobj=0.0f, vcls=0.0f;
  if (valid){
    float best = __uint_as_float(obju[gid]);   // max_t iou*invm (k1-scattered)
    float obj_t = ib ? fminf(fmaxf(best,0.0f),1.0f) : 0.0f;
    vobj = bce_fast(obja[gid], obj_t);

    int tp = 0; bool mpv = false;
    if (cnt > 1){ tp = bt; mpv = true; }
    else if (cnt == 1){
      tp = m0 ? (__ffsll(m0)-1) : (64 + __ffsll(m1)-1);
      mpv = true;
    }

    if (mpv){
      m = 1.0f;
      float4 T = tb4[tp];
      float x1=T.x, y1=T.y, x2=T.z, y2=T.w;
      float w = fmaxf(fminf(px2,x2)-fmaxf(px1,x1),0.0f);
      float h = fmaxf(fminf(py2,y2)-fmaxf(py1,y1),0.0f);
      float inter = w*h;
      float wp=px2-px1, hp=py2-py1, wt=x2-x1, ht=y2-y1;
      float iou = inter/(wp*hp + wt*ht - inter + 1e-8f);
      float cw = fmaxf(px2,x2)-fminf(px1,x1);
      float ch = fmaxf(py2,y2)-fminf(py1,y1);
      float c2 = cw*cw + ch*ch + 1e-8f;
      float dx = (px1+px2)-(x1+x2), dy = (py1+py2)-(y1+y2);
      float rho2 = (dx*dx + dy*dy)/4.0f;
      float da = atanf(wt/(ht+1e-8f)) - atanf(wp/(hp+1e-8f));
      float v  = 0.4052847345693511f * da * da;   // 4/pi^2
      float alpha = v/(1.0f - iou + v + 1e-8f);
      vbox = 1.0f - (iou - rho2/c2 - alpha*v);

      int cc = tcid[tp];
      float xcc = pred[(size_t)(i*NA + a)*PDIM + 5 + cc];
      vcls = (S0a[gid] - xcc) * (1.0f/80.0f);   // sum_c bce(x_c, onehot) = S0 - x_cc
    }
  }

  // wave-level reduce, one atomic quad per wave
  #pragma unroll
  for (int off=32; off>0; off>>=1){
    m    += __shfl_down(m, off);
    vbox += __shfl_down(vbox, off);
    vobj += __shfl_down(vobj, off);
    vcls += __shfl_down(vcls, off);
  }
  if ((threadIdx.x & 63) == 0){
    int slot = (blockIdx.x & 63)*4;
    atomicAdd(&acc[slot+0], m);
    atomicAdd(&acc[slot+1], vbox);
    atomicAdd(&acc[slot+2], vobj);
    atomicAdd(&acc[slot+3], vcls);
  }
}

// ---------------- Kernel 3: finalize (reduce 64 accumulator slots) -----------
__global__ void k3_final(const float* __restrict__ acc, float* __restrict__ out){
  int l = threadIdx.x;   // 64 threads
  float4 v = ((const float4*)acc)[l];
  #pragma unroll
  for (int off=32; off>0; off>>=1){
    v.x += __shfl_down(v.x, off);
    v.y += __shfl_down(v.y, off);
    v.z += __shfl_down(v.z, off);
    v.w += __shfl_down(v.w, off);
  }
  if (l == 0){
    float n    = fmaxf(v.x, 1.0f);
    float lbox = 0.05f * v.y / n;
    float lobj = v.z / (float)(NB*NA);
    float lcls = 0.5f  * v.w / n;
    out[0] = lbox + lobj + lcls;
    out[1] = lbox; out[2] = lobj; out[3] = lcls;
  }
}

extern "C" void kernel_launch(void* const* d_in, const int* in_sizes, int n_in,
                              void* d_out, int out_size, void* d_ws, size_t ws_size,
                              hipStream_t stream) {
  const float* pred    = (const float*)d_in[0];
  const float* target  = (const float*)d_in[1];
  const float* grid    = (const float*)d_in[2];
  const float* stridev = (const float*)d_in[3];
  float* out = (float*)d_out;

  char* ws = (char*)d_ws;

  size_t off = 0;
  unsigned long long* mask = (unsigned long long*)(ws + off); off += BAPC*16;
  float* acc    = (float*)(ws + off); off += 64*4*4;
  float4* pbox4 = (float4*)(ws + off); off += BAPC*16;
  float4* meta4 = (float4*)(ws + off); off += BAPC*16;
  float* obja   = (float*)(ws + off); off += BAPC*4;
  float* sobja  = (float*)(ws + off); off += BAPC*4;
  float* S0a    = (float*)(ws + off); off += BAPC*4;
  unsigned int* obju = (unsigned int*)(ws + off); off += BAPC*4;
  float* D      = (float*)(ws + off);
  const size_t need_d = off + (size_t)NCLS*BAPC*4;
  int use_d = (ws_size >= need_d) ? 1 : 0;

  // mask+acc+obju zeroed inside k0 (no memset dispatch)
  k0_precompute<<<NB*BPI, 256, 0, stream>>>(pred, target, grid, stridev,
                                            pbox4, meta4, obja, sobja, S0a, D, use_d,
                                            mask, obju, acc);
  k1_pertarget <<<NB*NT,  256, 0, stream>>>(pbox4, meta4, D, use_d,
                                            sobja, pred, target, obju, mask);
  k2_peranchor <<<NB*BPI2, 256, 0, stream>>>(pred, pbox4, meta4, obja, sobja, S0a,
                                             D, use_d, target, obju, mask, acc);
  k3_final     <<<1, 64, 0, stream>>>(acc, out);
}

// Round 4
// 202.596 us; speedup vs baseline: 1.1395x; 1.1318x over previous
//
#include <hip/hip_runtime.h>
#include <cfloat>

#pragma clang fp contract(off)

#define NCLS 80
#define PDIM 85
#define NA   8400
#define NAP  8448          // padded per-image anchor stride = 33*256 (BPI*64)
#define NB   16
#define NT   128
#define NTOP 10
#define APB  64      // anchors per k0 block
#define BPI  132     // ceil(NA/64) ; BPI*64 == NAP
#define BPI2 33      // k2: 256 anchors per block ; BPI2*256 == NAP
#define LN2  0.6931471805599453f
#define CAPW 768     // per-wave compaction capacity (int entries; worst case ~300)

#define BAPC ((size_t)NB*NAP)

#define KSENT 0xFFFFFFFF7FFFFFFFull   // sentinel key: huge cost, idx 0x7FFFFFFF

// fast native sigmoid: rcp(1+exp(-x)).
__device__ __forceinline__ float sigm_fast(float x){
  float e = __expf(-x);
  return __builtin_amdgcn_rcpf(1.0f + e);
}

// fast bce (value path only)
__device__ __forceinline__ float bce_fast(float x, float t){
  float ax = fabsf(x);
  float e  = __expf(-ax);
  return fmaxf(x,0.0f) - x*t + LN2*__builtin_amdgcn_logf(1.0f + e);
}

// Fast-rcp IoU. Used identically in k1 (topk + obj re-walk) and k2 -> consistent.
__device__ __forceinline__ float pair_iou(float tx1,float ty1,float tx2,float ty2,
                                          float px1,float py1,float px2,float py2){
  float w = fminf(tx2,px2) - fmaxf(tx1,px1);
  float h = fminf(ty2,py2) - fmaxf(ty1,py1);
  w = fmaxf(w,0.0f); h = fmaxf(h,0.0f);
  float inter = w*h;
  float at = fmaxf(tx2-tx1,0.0f)*fmaxf(ty2-ty1,0.0f);
  float ap = fmaxf(px2-px1,0.0f)*fmaxf(py2-py1,0.0f);
  float den = at+ap-inter+1e-8f;
  return inter * __builtin_amdgcn_rcpf(den);
}

// dval fallback (use_d==0 only; normally D table is used)
__device__ __forceinline__ float dval_fn(float sobj, float lg){
  float ln_sobj = LN2*__builtin_amdgcn_logf(sobj);
  float e = __expf(-fabsf(lg));
  float L = LN2*__builtin_amdgcn_logf(1.0f + e);
  float ln_sc = -(fmaxf(-lg,0.0f) + L);
  float lph = 0.5f*(ln_sobj + ln_sc);
  float p = __expf(lph);
  float lp = fmaxf(lph, -100.0f);
  float l1 = fmaxf(LN2*__builtin_amdgcn_logf(fmaxf(1.0f - p, 0.0f)), -100.0f);
  return lp - l1;
}

// Selection-critical: identical in k1 top-k and k2 argmin (same inline, contract off).
__device__ __forceinline__ float cost_from(float S, float dval, float iou, bool ibc, bool ib){
  float iouc = -LN2 * __builtin_amdgcn_logf(iou + 1e-8f);
  float clsc = -(S + dval);
  float c = clsc + 3.0f*iouc;
  c = c + (ibc ? 0.0f : 100000.0f);
  c = c + (ib  ? 0.0f : 1000000000.0f);
  return c;
}

// sortable u64 key: ascending key order == ascending (cost, idx) lexicographic
__device__ __forceinline__ unsigned long long key_of(float c, int idx){
  unsigned int u = __float_as_uint(c);
  u ^= (u & 0x80000000u) ? 0xFFFFFFFFu : 0x80000000u;
  return ((unsigned long long)u << 32) | (unsigned int)idx;
}

// sorted-insert helpers (branchless unrolled shift; order-independent)
__device__ __forceinline__ void ins_iou(float* riou, float iou){
  if (iou > riou[NTOP-1]){
    #pragma unroll
    for (int j = NTOP-1; j >= 1; --j){
      bool gj  = iou > riou[j];
      bool gj1 = iou > riou[j-1];
      riou[j] = gj ? (gj1 ? riou[j-1] : iou) : riou[j];
    }
    riou[0] = (iou > riou[0]) ? iou : riou[0];
  }
}
__device__ __forceinline__ void ins_key(unsigned long long* rk, unsigned long long key){
  if (key < rk[NTOP-1]){
    #pragma unroll
    for (int j = NTOP-1; j >= 1; --j){
      bool bj  = key < rk[j];
      bool bj1 = key < rk[j-1];
      rk[j] = bj ? (bj1 ? rk[j-1] : key) : rk[j];
    }
    rk[0] = (key < rk[0]) ? key : rk[0];
  }
}

// ---------------- Kernel 0: transpose + per-anchor precompute ----------------
__global__ __launch_bounds__(256) void k0_precompute(
    const float* __restrict__ pred, const float* __restrict__ target,
    const float* __restrict__ grid, const float* __restrict__ stridev,
    float4* __restrict__ pbox4, float4* __restrict__ meta4,
    float* __restrict__ obja, float* __restrict__ sobja,
    float* __restrict__ S0a, float* __restrict__ D, int use_d,
    unsigned long long* __restrict__ mask, unsigned int* __restrict__ obju,
    float* __restrict__ acc)
{
  __shared__ float  tile[APB*PDIM];   // [a][c], stride 85 (odd -> conflict-free)
  __shared__ float4 tb4s[NT];
  __shared__ float  ps_s[4][APB];
  __shared__ float  ps0_s[4][APB];
  __shared__ int    ib_s[4][APB];

  int i  = blockIdx.x / BPI;
  int b  = blockIdx.x % BPI;
  int c0 = b*APB;
  int n  = NA - c0; if (n > APB) n = APB;
  int tid = threadIdx.x;

  if (blockIdx.x == 0) acc[tid] = 0.0f;   // 256 slots

  const float* src = pred + ((size_t)i*NA + c0)*PDIM;
  int tot = n*PDIM;
  for (int idx = tid; idx < tot; idx += 256) tile[idx] = src[idx];
  for (int idx = tid; idx < NT; idx += 256){
    const float* tg = target + (i*NT + idx)*6;
    tb4s[idx] = make_float4(tg[2],tg[3],tg[4],tg[5]);
  }
  __syncthreads();

  int al = tid & 63, cg = tid >> 6;
  if (al < n){
    int gid = i*NAP + c0 + al;
    // softplus identity: ln sigm(x) = -(max(-x,0)+L), L = ln(1+exp(-|x|))
    float x4 = tile[al*PDIM+4];
    float e4 = __expf(-fabsf(x4));
    float L4 = LN2*__builtin_amdgcn_logf(1.0f + e4);
    float ln_sobj = -(fmaxf(-x4,0.0f) + L4);
    float ps = 0.0f, ps0 = 0.0f;
    #pragma unroll 4
    for (int k = 0; k < 20; ++k){
      int c = cg*20 + k;
      float x  = tile[al*PDIM+5+c];
      float e  = __expf(-fabsf(x));
      float L  = LN2*__builtin_amdgcn_logf(1.0f + e);
      float ln_sc = -(fmaxf(-x,0.0f) + L);
      float lph = 0.5f*(ln_sobj + ln_sc);     // ln p = 0.5 ln(sobj*sc)
      float p   = __expf(lph);
      float lp  = fmaxf(lph, -100.0f);
      float l1  = fmaxf(LN2*__builtin_amdgcn_logf(fmaxf(1.0f - p, 0.0f)), -100.0f);
      ps  += l1;
      if (use_d) D[(size_t)c*BAPC + gid] = lp - l1;
      ps0 += fmaxf(x,0.0f) + L;               // bce(x,0) reuses L
    }
    ps_s[cg][al] = ps; ps0_s[cg][al] = ps0;

    int ga = c0 + al;
    float xg = grid[2*ga], yg = grid[2*ga+1], sv = stridev[ga];
    float xc = (xg + 0.5f)*sv, yc = (yg + 0.5f)*sv;
    float rc = 2.5f*sv;
    bool ibp = false;
    #pragma unroll 4
    for (int t = cg*32; t < cg*32+32; ++t){
      float4 T = tb4s[t];
      bool inb = (xc-T.x>0.0f)&&(yc-T.y>0.0f)&&(T.z-xc>0.0f)&&(T.w-yc>0.0f);
      float txc=(T.x+T.z)*0.5f, tyc=(T.y+T.w)*0.5f;
      bool inc = fmaxf(fabsf(xc-txc),fabsf(yc-tyc)) < rc;
      ibp = ibp || inb || inc;
    }
    ib_s[cg][al] = ibp ? 1 : 0;
  }
  __syncthreads();

  if (tid < n){
    int a = tid;
    int gid = i*NAP + c0 + a;
    float s  = ps_s[0][a]  + ps_s[1][a]  + ps_s[2][a]  + ps_s[3][a];
    float s0 = ps0_s[0][a] + ps0_s[1][a] + ps0_s[2][a] + ps0_s[3][a];
    bool ib  = (ib_s[0][a] | ib_s[1][a] | ib_s[2][a] | ib_s[3][a]) != 0;

    float x1 = tile[a*PDIM+0], y1 = tile[a*PDIM+1];
    float x2 = tile[a*PDIM+2], y2 = tile[a*PDIM+3];
    float ol = tile[a*PDIM+4];
    pbox4[gid] = make_float4(x1,y1,x2,y2);
    obja[gid]  = ol;
    sobja[gid] = sigm_fast(ol);
    S0a[gid]   = s0;
    mask[(size_t)gid*2]   = 0ull;   // replaces host-side memset
    mask[(size_t)gid*2+1] = 0ull;
    obju[gid] = 0u;                 // obj-target accumulator (f32-as-u32, >=0)

    int ga = c0 + a;
    float xg = grid[2*ga], yg = grid[2*ga+1], sv = stridev[ga];
    float xc = (xg + 0.5f)*sv, yc = (yg + 0.5f)*sv;
    float rc = 2.5f*sv;
    meta4[gid] = make_float4(xc, yc, ib ? rc : -rc, s);  // sign(z) = in_box
  } else if (tid < APB){
    // pad anchors (only last block per image, n=16): never active in k1/k2
    int gid = i*NAP + c0 + tid;
    meta4[gid] = make_float4(0.0f, 0.0f, -1.0f, 0.0f);
    pbox4[gid] = make_float4(0.0f, 0.0f, 0.0f, 0.0f);
    obju[gid]  = 0u;
  }
}

// ---- Kernel 1: per-target compact scan + register tournament top-k ----------
// Phase 1: cheap candidacy test only (7-op overlap == iou>0 exactly).
// Phase 2: full IoU/cost over the ~2-4% candidates.
// Phase 3: re-walk candidates, scatter per-anchor obj target via atomicMax.
__global__ __launch_bounds__(256) void k1_pertarget(
    const float4* __restrict__ pbox4, const float4* __restrict__ meta4,
    const float* __restrict__ D, int use_d,
    const float* __restrict__ sobja, const float* __restrict__ pred,
    const float* __restrict__ target,
    unsigned int* __restrict__ obju, unsigned long long* __restrict__ mask)
{
  __shared__ int   seg[4*CAPW];                      // 12 KB (index | ibc<<15)
  __shared__ int   cnts_s[4], cibc_s[4];
  __shared__ float wiou[4][NTOP];                    // per-wave desc iou
  __shared__ unsigned long long wkey[4][NTOP];       // per-wave asc cost keys
  __shared__ float rmax_s;

  int tid = threadIdx.x, lane = tid & 63, w = tid >> 6;
  int g = blockIdx.x;
  int i = g / NT, t = g - i*NT;
  int iNAP = i*NAP;
  int iNA  = i*NA;
  const float* m4f = (const float*)meta4;

  const float* tg = target + (size_t)g*6;
  int   cid = (int)tg[1];
  float tx1 = tg[2], ty1 = tg[3], tx2 = tg[4], ty2 = tg[5];
  float txc = (tx1+tx2)*0.5f, tyc = (ty1+ty2)*0.5f;
  const float* Dc = use_d ? (D + (size_t)cid*BAPC) : nullptr;

  // ---- phase 1: prefetched cheap scan, per-wave compaction (no IoU) ----
  int cnt = 0, ci = 0;
  int a = w*64 + lane;
  float4 pb = pbox4[iNAP+a];
  float4 mt = meta4[iNAP+a];
  for (int k = 0; k < 33; ++k){
    int a2 = a + 256;
    int ld = (a2 < NAP) ? a2 : 0;      // last prefetch discarded
    float4 pbn = pbox4[iNAP+ld];
    float4 mtn = meta4[iNAP+ld];

    bool act = (mt.z > 0.0f);          // in_box-any; pads have z=-1
    // strict overlap == (iou > 0): inter>0 iff both extents positive
    bool ov  = (fminf(tx2,pb.z) > fmaxf(tx1,pb.x)) &&
               (fminf(ty2,pb.w) > fmaxf(ty1,pb.y));
    bool inb = (mt.x-tx1>0.0f)&&(mt.y-ty1>0.0f)&&(tx2-mt.x>0.0f)&&(ty2-mt.y>0.0f);
    bool inc = fmaxf(fabsf(mt.x-txc),fabsf(mt.y-tyc)) < mt.z;
    bool ibc = inb && inc;             // ibc => inb => act (for real anchors)
    bool cand = act && (ov || ibc);
    unsigned long long bb  = __ballot(cand);
    unsigned long long bb2 = __ballot(ibc);
    if (cand){
      int pos = cnt + __popcll(bb & ((1ull << lane) - 1ull));
      if (pos < CAPW) seg[w*CAPW + pos] = a | (ibc ? (1<<15) : 0);
    }
    cnt += __popcll(bb);
    ci  += __popcll(bb2);
    pb = pbn; mt = mtn; a = a2;
  }
  if (lane == 0){ cnts_s[w] = cnt; cibc_s[w] = ci; }
  __syncthreads();

  int tibc = cibc_s[0]+cibc_s[1]+cibc_s[2]+cibc_s[3];
  bool ovf = (cnts_s[0]>CAPW)||(cnts_s[1]>CAPW)||(cnts_s[2]>CAPW)||(cnts_s[3]>CAPW);
  bool fastp = !ovf && (tibc >= 16);

  float riou[NTOP]; unsigned long long rk[NTOP];
  #pragma unroll
  for (int j=0;j<NTOP;++j){ riou[j]=0.0f; rk[j]=KSENT; }

  int cw = cnts_s[w];
  if (fastp){
    for (int j = lane; j < cw; j += 64){
      int e  = seg[w*CAPW + j];
      int a1 = e & 0x3fff;
      bool ibc = (e & (1<<15)) != 0;
      int gid = iNAP + a1;
      float4 pb2 = pbox4[gid];                      // L2-hot gather
      float iou = pair_iou(tx1,ty1,tx2,ty2, pb2.x,pb2.y,pb2.z,pb2.w);
      ins_iou(riou, iou);
      float S  = m4f[(size_t)gid*4 + 3];
      float dv = use_d ? Dc[gid] : dval_fn(sobja[gid], pred[(size_t)(iNA+a1)*PDIM + 5 + cid]);
      float c  = cost_from(S, dv, iou, ibc, true);
      ins_key(rk, key_of(c, a1));
    }
  } else {
    // exact fallback: full rescan by all 256 threads (rare)
    for (int a1 = tid; a1 < NA; a1 += 256){
      float4 mt2 = meta4[iNAP+a1];
      if (mt2.z > 0.0f){
        float4 pb2 = pbox4[iNAP+a1];
        float iou = pair_iou(tx1,ty1,tx2,ty2, pb2.x,pb2.y,pb2.z,pb2.w);
        ins_iou(riou, iou);
        bool inb = (mt2.x-tx1>0.0f)&&(mt2.y-ty1>0.0f)&&(tx2-mt2.x>0.0f)&&(ty2-mt2.y>0.0f);
        bool inc = fmaxf(fabsf(mt2.x-txc),fabsf(mt2.y-tyc)) < mt2.z;
        float dv = use_d ? Dc[iNAP+a1] : dval_fn(sobja[iNAP+a1], pred[(size_t)(iNA+a1)*PDIM + 5 + cid]);
        float c = cost_from(mt2.w, dv, iou, inb&&inc, true);
        ins_key(rk, key_of(c, a1));
      }
    }
  }

  // ---- per-wave tournament pop: 10 rounds wave-reduce + winner-pop ----
  #pragma unroll
  for (int r = 0; r < NTOP; ++r){
    float gm = riou[0];
    #pragma unroll
    for (int m = 1; m < 64; m <<= 1) gm = fmaxf(gm, __shfl_xor(gm, m));
    unsigned long long bb = __ballot(riou[0] == gm);
    int win = __ffsll(bb) - 1;
    if (lane == win){
      #pragma unroll
      for (int j=0;j<NTOP-1;++j) riou[j] = riou[j+1];
      riou[NTOP-1] = 0.0f;
    }
    if (lane == 0) wiou[w][r] = gm;
  }
  #pragma unroll
  for (int r = 0; r < NTOP; ++r){
    unsigned long long gk = rk[0];
    #pragma unroll
    for (int m = 1; m < 64; m <<= 1){
      unsigned long long o = __shfl_xor(gk, m);
      gk = (o < gk) ? o : gk;
    }
    unsigned long long bb = __ballot(rk[0] == gk);
    int win = __ffsll(bb) - 1;
    if (lane == win){
      #pragma unroll
      for (int j=0;j<NTOP-1;++j) rk[j] = rk[j+1];
      rk[NTOP-1] = KSENT;
    }
    if (lane == 0) wkey[w][r] = gk;
  }
  __syncthreads();

  // ---- wave 0: 4-way pointer merge for iou (global desc order, like jnp) ----
  int dk = 1;
  if (w == 0){
    int p0=0,p1=0,p2=0,p3=0;
    float ssum = 0.0f, rmax = 0.0f;
    #pragma unroll
    for (int r = 0; r < NTOP; ++r){
      float v0=wiou[0][p0], v1=wiou[1][p1], v2=wiou[2][p2], v3=wiou[3][p3];
      float mx = fmaxf(fmaxf(v0,v1), fmaxf(v2,v3));
      if (r == 0) rmax = mx;
      ssum += mx;
      if      (mx == v0) ++p0;
      else if (mx == v1) ++p1;
      else if (mx == v2) ++p2;
      else               ++p3;
    }
    dk = (int)ssum;
    if (dk < 1) dk = 1;
    if (lane == 0) rmax_s = rmax;
  }
  __syncthreads();

  // ---- phase 3: obj-target scatter over candidates (all 4 waves) ----
  // Bitwise-identical to the reference obj computation: same pair_iou, same
  // 1/(rmax+1e-8) divide; fmax via atomicMax over nonneg floats (uint order
  // == float order).
  float invm = 1.0f / (rmax_s + 1e-8f);
  if (fastp){
    for (int j = lane; j < cw; j += 64){
      int a1 = seg[w*CAPW + j] & 0x3fff;
      int gid = iNAP + a1;
      float4 pb2 = pbox4[gid];
      float iou = pair_iou(tx1,ty1,tx2,ty2, pb2.x,pb2.y,pb2.z,pb2.w);
      float v = iou * invm;
      if (v > 0.0f) atomicMax(&obju[gid], __float_as_uint(v));
    }
  } else {
    for (int a1 = tid; a1 < NA; a1 += 256){
      float4 mt2 = meta4[iNAP+a1];
      if (mt2.z > 0.0f){
        float4 pb2 = pbox4[iNAP+a1];
        float iou = pair_iou(tx1,ty1,tx2,ty2, pb2.x,pb2.y,pb2.z,pb2.w);
        float v = iou * invm;
        if (v > 0.0f) atomicMax(&obju[iNAP+a1], __float_as_uint(v));
      }
    }
  }

  // ---- wave 0: 4-way pointer merge for cost keys + mask scatter ----
  if (w == 0){
    int q0=0,q1=0,q2=0,q3=0;
    int myidx = 0x7fffffff;
    #pragma unroll
    for (int r = 0; r < NTOP; ++r){
      unsigned long long k0=wkey[0][q0], k1=wkey[1][q1], k2=wkey[2][q2], k3=wkey[3][q3];
      unsigned long long mn = k0;
      mn = (k1 < mn) ? k1 : mn;
      mn = (k2 < mn) ? k2 : mn;
      mn = (k3 < mn) ? k3 : mn;
      if (lane == r) myidx = (int)(mn & 0xFFFFFFFFull);
      if      (mn == k0) ++q0;
      else if (mn == k1) ++q1;
      else if (mn == k2) ++q2;
      else               ++q3;
    }

    if (lane < NTOP && lane < dk){
      int a1 = myidx;
      if (a1 >= 0 && a1 < NA){     // sentinel idx = 0x7FFFFFFF skipped
        atomicOr(&mask[(size_t)(iNAP + a1)*2 + (t>>6)], 1ull << (t & 63));
      }
    }
  }
}

// ---------- Kernel 2: per-anchor resolution + loss partial sums --------------
// Conflicted anchors (cnt>1, ~3%) are BLOCK-COMPACTED into an LDS worklist:
// only ~1 wave/block runs the 128-target argmin (vs ~all waves paying via
// exec-mask in rounds 1-3 -- the 84us latency tail), and its D gathers are
// batched 16-deep (fully-unrolled regs) so the chain is 8x600cy, not 128x600.
__global__ __launch_bounds__(256) void k2_peranchor(
    const float* __restrict__ pred,
    const float4* __restrict__ pbox4, const float4* __restrict__ meta4,
    const float* __restrict__ obja, const float* __restrict__ sobja,
    const float* __restrict__ S0a,
    const float* __restrict__ D, int use_d,
    const float* __restrict__ target,
    const unsigned int* __restrict__ obju, const unsigned long long* __restrict__ mask,
    float* __restrict__ acc)
{
  __shared__ float4 tb4[NT];
  __shared__ int    tcid[NT];
  __shared__ int    cl[256];     // compacted conflicted-anchor thread ids
  __shared__ int    bt_s[256];   // per-anchor argmin result
  __shared__ int    ncl;

  int i  = blockIdx.x / BPI2;
  int b  = blockIdx.x - i*BPI2;
  int a  = b*256 + threadIdx.x;        // 0..NAP-1
  int gid = i*NAP + a;
  int tid = threadIdx.x, lane = tid & 63;

  if (tid < NT){
    const float* tg = target + (i*NT + tid)*6;
    tcid[tid] = (int)tg[1];
    tb4[tid]  = make_float4(tg[2],tg[3],tg[4],tg[5]);
  }
  if (tid == 0) ncl = 0;
  __syncthreads();

  bool valid = (a < NA);
  float4 pb = pbox4[gid];              // pads: zero box (k0-initialized)
  float4 mt = meta4[gid];              // pads: z=-1
  bool ib = valid && (mt.z > 0.0f);
  float px1=pb.x, py1=pb.y, px2=pb.z, py2=pb.w;

  unsigned long long m0=0, m1=0;
  if (valid){ m0 = mask[(size_t)gid*2]; m1 = mask[(size_t)gid*2+1]; }
  int cnt = __popcll(m0) + __popcll(m1);

  // ---- compact conflicted anchors into cl[] (per-wave ballot + LDS base) ----
  bool myc = (cnt > 1);
  unsigned long long cb = __ballot(myc);
  int nb = __popcll(cb);
  int base = 0;
  if (lane == 0 && nb) base = atomicAdd(&ncl, nb);
  base = __shfl(base, 0);
  if (myc) cl[base + __popcll(cb & ((1ull << lane) - 1ull))] = tid;
  __syncthreads();

  // ---- worker pass: strided over compacted list, 16-deep gather batching ----
  int tot = ncl;
  for (int j = tid; j < tot; j += 256){
    int aidx = cl[j];
    int a2g  = b*256 + aidx;
    int gid2 = i*NAP + a2g;
    float4 pb2 = pbox4[gid2];
    float4 mt2 = meta4[gid2];
    bool ib2 = (mt2.z > 0.0f);
    float rc2 = fabsf(mt2.z);
    float Sg  = mt2.w;
    float sobj = use_d ? 0.0f : sobja[gid2];
    size_t pbase = (size_t)(i*NA + a2g)*PDIM;

    float bc = FLT_MAX; int bt = NT;
    for (int t0 = 0; t0 < NT; t0 += 16){
      float dv[16];
      #pragma unroll
      for (int u = 0; u < 16; ++u)
        dv[u] = use_d ? D[(size_t)tcid[t0+u]*BAPC + gid2]
                      : dval_fn(sobj, pred[pbase + 5 + tcid[t0+u]]);
      #pragma unroll
      for (int u = 0; u < 16; ++u){
        int t = t0 + u;
        float4 T = tb4[t];
        float iou = ib2 ? pair_iou(T.x,T.y,T.z,T.w,pb2.x,pb2.y,pb2.z,pb2.w) : 0.0f;
        bool inb = (mt2.x-T.x>0.0f)&&(mt2.y-T.y>0.0f)&&(T.z-mt2.x>0.0f)&&(T.w-mt2.y>0.0f);
        float txc=(T.x+T.z)*0.5f, tyc=(T.y+T.w)*0.5f;
        bool inc = fmaxf(fabsf(mt2.x-txc),fabsf(mt2.y-tyc)) < rc2;
        float c = cost_from(Sg, dv[u], iou, inb&&inc, ib2);
        if (c < bc){ bc = c; bt = t; }   // ascending t, strict < == ref argmin
      }
    }
    bt_s[aidx] = bt;
  }
  __syncthreads();

  float m=0.0f, vbox=0.0f, vobj=0.0f, vcls=0.0f;
  if (valid){
    float best = __uint_as_float(obju[gid]);   // max_t iou*invm (k1-scattered)
    float obj_t = ib ? fminf(fmaxf(best,0.0f),1.0f) : 0.0f;
    vobj = bce_fast(obja[gid], obj_t);

    int tp = 0; bool mpv = false;
    if (cnt > 1){ tp = bt_s[tid]; mpv = true; }
    else if (cnt == 1){
      tp = m0 ? (__ffsll(m0)-1) : (64 + __ffsll(m1)-1);
      mpv = true;
    }

    if (mpv){
      m = 1.0f;
      float4 T = tb4[tp];
      float x1=T.x, y1=T.y, x2=T.z, y2=T.w;
      float w = fmaxf(fminf(px2,x2)-fmaxf(px1,x1),0.0f);
      float h = fmaxf(fminf(py2,y2)-fmaxf(py1,y1),0.0f);
      float inter = w*h;
      float wp=px2-px1, hp=py2-py1, wt=x2-x1, ht=y2-y1;
      float iou = inter/(wp*hp + wt*ht - inter + 1e-8f);
      float cw = fmaxf(px2,x2)-fminf(px1,x1);
      float ch = fmaxf(py2,y2)-fminf(py1,y1);
      float c2 = cw*cw + ch*ch + 1e-8f;
      float dx = (px1+px2)-(x1+x2), dy = (py1+py2)-(y1+y2);
      float rho2 = (dx*dx + dy*dy)/4.0f;
      float da = atanf(wt/(ht+1e-8f)) - atanf(wp/(hp+1e-8f));
      float v  = 0.4052847345693511f * da * da;   // 4/pi^2
      float alpha = v/(1.0f - iou + v + 1e-8f);
      vbox = 1.0f - (iou - rho2/c2 - alpha*v);

      int cc = tcid[tp];
      float xcc = pred[(size_t)(i*NA + a)*PDIM + 5 + cc];
      vcls = (S0a[gid] - xcc) * (1.0f/80.0f);   // sum_c bce(x_c, onehot) = S0 - x_cc
    }
  }

  // wave-level reduce, one atomic quad per wave
  #pragma unroll
  for (int off=32; off>0; off>>=1){
    m    += __shfl_down(m, off);
    vbox += __shfl_down(vbox, off);
    vobj += __shfl_down(vobj, off);
    vcls += __shfl_down(vcls, off);
  }
  if ((threadIdx.x & 63) == 0){
    int slot = (blockIdx.x & 63)*4;
    atomicAdd(&acc[slot+0], m);
    atomicAdd(&acc[slot+1], vbox);
    atomicAdd(&acc[slot+2], vobj);
    atomicAdd(&acc[slot+3], vcls);
  }
}

// ---------------- Kernel 3: finalize (reduce 64 accumulator slots) -----------
__global__ void k3_final(const float* __restrict__ acc, float* __restrict__ out){
  int l = threadIdx.x;   // 64 threads
  float4 v = ((const float4*)acc)[l];
  #pragma unroll
  for (int off=32; off>0; off>>=1){
    v.x += __shfl_down(v.x, off);
    v.y += __shfl_down(v.y, off);
    v.z += __shfl_down(v.z, off);
    v.w += __shfl_down(v.w, off);
  }
  if (l == 0){
    float n    = fmaxf(v.x, 1.0f);
    float lbox = 0.05f * v.y / n;
    float lobj = v.z / (float)(NB*NA);
    float lcls = 0.5f  * v.w / n;
    out[0] = lbox + lobj + lcls;
    out[1] = lbox; out[2] = lobj; out[3] = lcls;
  }
}

extern "C" void kernel_launch(void* const* d_in, const int* in_sizes, int n_in,
                              void* d_out, int out_size, void* d_ws, size_t ws_size,
                              hipStream_t stream) {
  const float* pred    = (const float*)d_in[0];
  const float* target  = (const float*)d_in[1];
  const float* grid    = (const float*)d_in[2];
  const float* stridev = (const float*)d_in[3];
  float* out = (float*)d_out;

  char* ws = (char*)d_ws;

  size_t off = 0;
  unsigned long long* mask = (unsigned long long*)(ws + off); off += BAPC*16;
  float* acc    = (float*)(ws + off); off += 64*4*4;
  float4* pbox4 = (float4*)(ws + off); off += BAPC*16;
  float4* meta4 = (float4*)(ws + off); off += BAPC*16;
  float* obja   = (float*)(ws + off); off += BAPC*4;
  float* sobja  = (float*)(ws + off); off += BAPC*4;
  float* S0a    = (float*)(ws + off); off += BAPC*4;
  unsigned int* obju = (unsigned int*)(ws + off); off += BAPC*4;
  float* D      = (float*)(ws + off);
  const size_t need_d = off + (size_t)NCLS*BAPC*4;
  int use_d = (ws_size >= need_d) ? 1 : 0;

  // mask+acc+obju zeroed inside k0 (no memset dispatch)
  k0_precompute<<<NB*BPI, 256, 0, stream>>>(pred, target, grid, stridev,
                                            pbox4, meta4, obja, sobja, S0a, D, use_d,
                                            mask, obju, acc);
  k1_pertarget <<<NB*NT,  256, 0, stream>>>(pbox4, meta4, D, use_d,
                                            sobja, pred, target, obju, mask);
  k2_peranchor <<<NB*BPI2, 256, 0, stream>>>(pred, pbox4, meta4, obja, sobja, S0a,
                                             D, use_d, target, obju, mask, acc);
  k3_final     <<<1, 64, 0, stream>>>(acc, out);
}

// Round 5
// 160.262 us; speedup vs baseline: 1.4406x; 1.2642x over previous
//
#include <hip/hip_runtime.h>
#include <cfloat>

#pragma clang fp contract(off)

#define NCLS 80
#define PDIM 85
#define NA   8400
#define NAP  8448          // padded per-image anchor stride = 33*256 (BPI*64)
#define NB   16
#define NT   128
#define NTOP 10
#define APB  64      // anchors per k0 block
#define BPI  132     // ceil(NA/64) ; BPI*64 == NAP
#define BPI2 33      // k2: 256 anchors per block ; BPI2*256 == NAP
#define LN2  0.6931471805599453f
#define CAPW 768     // per-wave compaction capacity (int entries; worst case ~300)

#define BAPC ((size_t)NB*NAP)

#define KSENT 0xFFFFFFFF7FFFFFFFull   // sentinel key: huge cost, idx 0x7FFFFFFF

// fast native sigmoid: rcp(1+exp(-x)).
__device__ __forceinline__ float sigm_fast(float x){
  float e = __expf(-x);
  return __builtin_amdgcn_rcpf(1.0f + e);
}

// fast bce (value path only)
__device__ __forceinline__ float bce_fast(float x, float t){
  float ax = fabsf(x);
  float e  = __expf(-ax);
  return fmaxf(x,0.0f) - x*t + LN2*__builtin_amdgcn_logf(1.0f + e);
}

// Fast-rcp IoU. Used identically in k1 (topk + obj re-walk) and k2 -> consistent.
__device__ __forceinline__ float pair_iou(float tx1,float ty1,float tx2,float ty2,
                                          float px1,float py1,float px2,float py2){
  float w = fminf(tx2,px2) - fmaxf(tx1,px1);
  float h = fminf(ty2,py2) - fmaxf(ty1,py1);
  w = fmaxf(w,0.0f); h = fmaxf(h,0.0f);
  float inter = w*h;
  float at = fmaxf(tx2-tx1,0.0f)*fmaxf(ty2-ty1,0.0f);
  float ap = fmaxf(px2-px1,0.0f)*fmaxf(py2-py1,0.0f);
  float den = at+ap-inter+1e-8f;
  return inter * __builtin_amdgcn_rcpf(den);
}

// dval fallback (use_d==0 only; normally D table is used)
__device__ __forceinline__ float dval_fn(float sobj, float lg){
  float ln_sobj = LN2*__builtin_amdgcn_logf(sobj);
  float e = __expf(-fabsf(lg));
  float L = LN2*__builtin_amdgcn_logf(1.0f + e);
  float ln_sc = -(fmaxf(-lg,0.0f) + L);
  float lph = 0.5f*(ln_sobj + ln_sc);
  float p = __expf(lph);
  float lp = fmaxf(lph, -100.0f);
  float l1 = fmaxf(LN2*__builtin_amdgcn_logf(fmaxf(1.0f - p, 0.0f)), -100.0f);
  return lp - l1;
}

// Selection-critical: identical in k1 top-k and k2 argmin (same inline, contract off).
__device__ __forceinline__ float cost_from(float S, float dval, float iou, bool ibc, bool ib){
  float iouc = -LN2 * __builtin_amdgcn_logf(iou + 1e-8f);
  float clsc = -(S + dval);
  float c = clsc + 3.0f*iouc;
  c = c + (ibc ? 0.0f : 100000.0f);
  c = c + (ib  ? 0.0f : 1000000000.0f);
  return c;
}

// sortable u64 key: ascending key order == ascending (cost, idx) lexicographic
__device__ __forceinline__ unsigned long long key_of(float c, int idx){
  unsigned int u = __float_as_uint(c);
  u ^= (u & 0x80000000u) ? 0xFFFFFFFFu : 0x80000000u;
  return ((unsigned long long)u << 32) | (unsigned int)idx;
}

// sorted-insert helpers (branchless unrolled shift; order-independent)
__device__ __forceinline__ void ins_iou(float* riou, float iou){
  if (iou > riou[NTOP-1]){
    #pragma unroll
    for (int j = NTOP-1; j >= 1; --j){
      bool gj  = iou > riou[j];
      bool gj1 = iou > riou[j-1];
      riou[j] = gj ? (gj1 ? riou[j-1] : iou) : riou[j];
    }
    riou[0] = (iou > riou[0]) ? iou : riou[0];
  }
}
__device__ __forceinline__ void ins_key(unsigned long long* rk, unsigned long long key){
  if (key < rk[NTOP-1]){
    #pragma unroll
    for (int j = NTOP-1; j >= 1; --j){
      bool bj  = key < rk[j];
      bool bj1 = key < rk[j-1];
      rk[j] = bj ? (bj1 ? rk[j-1] : key) : rk[j];
    }
    rk[0] = (key < rk[0]) ? key : rk[0];
  }
}

// ---------------- Kernel 0: transpose + per-anchor precompute ----------------
__global__ __launch_bounds__(256) void k0_precompute(
    const float* __restrict__ pred, const float* __restrict__ target,
    const float* __restrict__ grid, const float* __restrict__ stridev,
    float4* __restrict__ pbox4, float4* __restrict__ meta4,
    float* __restrict__ obja, float* __restrict__ sobja,
    float* __restrict__ S0a, float* __restrict__ D, int use_d,
    unsigned long long* __restrict__ mask, unsigned int* __restrict__ obju,
    float* __restrict__ acc)
{
  __shared__ float  tile[APB*PDIM];   // [a][c], stride 85 (odd -> conflict-free)
  __shared__ float4 tb4s[NT];
  __shared__ float  ps_s[4][APB];
  __shared__ float  ps0_s[4][APB];
  __shared__ int    ib_s[4][APB];

  int i  = blockIdx.x / BPI;
  int b  = blockIdx.x % BPI;
  int c0 = b*APB;
  int n  = NA - c0; if (n > APB) n = APB;
  int tid = threadIdx.x;

  if (blockIdx.x == 0) acc[tid] = 0.0f;   // 256 slots

  const float* src = pred + ((size_t)i*NA + c0)*PDIM;
  int tot = n*PDIM;
  for (int idx = tid; idx < tot; idx += 256) tile[idx] = src[idx];
  for (int idx = tid; idx < NT; idx += 256){
    const float* tg = target + (i*NT + idx)*6;
    tb4s[idx] = make_float4(tg[2],tg[3],tg[4],tg[5]);
  }
  __syncthreads();

  int al = tid & 63, cg = tid >> 6;
  if (al < n){
    int gid = i*NAP + c0 + al;
    // softplus identity: ln sigm(x) = -(max(-x,0)+L), L = ln(1+exp(-|x|))
    float x4 = tile[al*PDIM+4];
    float e4 = __expf(-fabsf(x4));
    float L4 = LN2*__builtin_amdgcn_logf(1.0f + e4);
    float ln_sobj = -(fmaxf(-x4,0.0f) + L4);
    float ps = 0.0f, ps0 = 0.0f;
    #pragma unroll 4
    for (int k = 0; k < 20; ++k){
      int c = cg*20 + k;
      float x  = tile[al*PDIM+5+c];
      float e  = __expf(-fabsf(x));
      float L  = LN2*__builtin_amdgcn_logf(1.0f + e);
      float ln_sc = -(fmaxf(-x,0.0f) + L);
      float lph = 0.5f*(ln_sobj + ln_sc);     // ln p = 0.5 ln(sobj*sc)
      float p   = __expf(lph);
      float lp  = fmaxf(lph, -100.0f);
      float l1  = fmaxf(LN2*__builtin_amdgcn_logf(fmaxf(1.0f - p, 0.0f)), -100.0f);
      ps  += l1;
      if (use_d) D[(size_t)c*BAPC + gid] = lp - l1;
      ps0 += fmaxf(x,0.0f) + L;               // bce(x,0) reuses L
    }
    ps_s[cg][al] = ps; ps0_s[cg][al] = ps0;

    int ga = c0 + al;
    float xg = grid[2*ga], yg = grid[2*ga+1], sv = stridev[ga];
    float xc = (xg + 0.5f)*sv, yc = (yg + 0.5f)*sv;
    float rc = 2.5f*sv;
    bool ibp = false;
    #pragma unroll 4
    for (int t = cg*32; t < cg*32+32; ++t){
      float4 T = tb4s[t];
      bool inb = (xc-T.x>0.0f)&&(yc-T.y>0.0f)&&(T.z-xc>0.0f)&&(T.w-yc>0.0f);
      float txc=(T.x+T.z)*0.5f, tyc=(T.y+T.w)*0.5f;
      bool inc = fmaxf(fabsf(xc-txc),fabsf(yc-tyc)) < rc;
      ibp = ibp || inb || inc;
    }
    ib_s[cg][al] = ibp ? 1 : 0;
  }
  __syncthreads();

  if (tid < n){
    int a = tid;
    int gid = i*NAP + c0 + a;
    float s  = ps_s[0][a]  + ps_s[1][a]  + ps_s[2][a]  + ps_s[3][a];
    float s0 = ps0_s[0][a] + ps0_s[1][a] + ps0_s[2][a] + ps0_s[3][a];
    bool ib  = (ib_s[0][a] | ib_s[1][a] | ib_s[2][a] | ib_s[3][a]) != 0;

    float x1 = tile[a*PDIM+0], y1 = tile[a*PDIM+1];
    float x2 = tile[a*PDIM+2], y2 = tile[a*PDIM+3];
    float ol = tile[a*PDIM+4];
    pbox4[gid] = make_float4(x1,y1,x2,y2);
    obja[gid]  = ol;
    sobja[gid] = sigm_fast(ol);
    S0a[gid]   = s0;
    mask[(size_t)gid*2]   = 0ull;   // replaces host-side memset
    mask[(size_t)gid*2+1] = 0ull;
    obju[gid] = 0u;                 // obj-target accumulator (f32-as-u32, >=0)

    int ga = c0 + a;
    float xg = grid[2*ga], yg = grid[2*ga+1], sv = stridev[ga];
    float xc = (xg + 0.5f)*sv, yc = (yg + 0.5f)*sv;
    float rc = 2.5f*sv;
    meta4[gid] = make_float4(xc, yc, ib ? rc : -rc, s);  // sign(z) = in_box
  } else if (tid < APB){
    // pad anchors (only last block per image, n=16): never active in k1/k2
    int gid = i*NAP + c0 + tid;
    meta4[gid] = make_float4(0.0f, 0.0f, -1.0f, 0.0f);
    pbox4[gid] = make_float4(0.0f, 0.0f, 0.0f, 0.0f);
    obju[gid]  = 0u;
  }
}

// ---- Kernel 1: per-target compact scan + register tournament top-k ----------
// Phase 1: cheap candidacy test only (7-op overlap == iou>0 exactly).
// Phase 2: full IoU/cost over the ~2-4% candidates.
// Phase 3: re-walk candidates, scatter per-anchor obj target via atomicMax.
__global__ __launch_bounds__(256) void k1_pertarget(
    const float4* __restrict__ pbox4, const float4* __restrict__ meta4,
    const float* __restrict__ D, int use_d,
    const float* __restrict__ sobja, const float* __restrict__ pred,
    const float* __restrict__ target,
    unsigned int* __restrict__ obju, unsigned long long* __restrict__ mask)
{
  __shared__ int   seg[4*CAPW];                      // 12 KB (index | ibc<<15)
  __shared__ int   cnts_s[4], cibc_s[4];
  __shared__ float wiou[4][NTOP];                    // per-wave desc iou
  __shared__ unsigned long long wkey[4][NTOP];       // per-wave asc cost keys
  __shared__ float rmax_s;

  int tid = threadIdx.x, lane = tid & 63, w = tid >> 6;
  int g = blockIdx.x;
  int i = g / NT, t = g - i*NT;
  int iNAP = i*NAP;
  int iNA  = i*NA;
  const float* m4f = (const float*)meta4;

  const float* tg = target + (size_t)g*6;
  int   cid = (int)tg[1];
  float tx1 = tg[2], ty1 = tg[3], tx2 = tg[4], ty2 = tg[5];
  float txc = (tx1+tx2)*0.5f, tyc = (ty1+ty2)*0.5f;
  const float* Dc = use_d ? (D + (size_t)cid*BAPC) : nullptr;

  // ---- phase 1: prefetched cheap scan, per-wave compaction (no IoU) ----
  int cnt = 0, ci = 0;
  int a = w*64 + lane;
  float4 pb = pbox4[iNAP+a];
  float4 mt = meta4[iNAP+a];
  for (int k = 0; k < 33; ++k){
    int a2 = a + 256;
    int ld = (a2 < NAP) ? a2 : 0;      // last prefetch discarded
    float4 pbn = pbox4[iNAP+ld];
    float4 mtn = meta4[iNAP+ld];

    bool act = (mt.z > 0.0f);          // in_box-any; pads have z=-1
    // strict overlap == (iou > 0): inter>0 iff both extents positive
    bool ov  = (fminf(tx2,pb.z) > fmaxf(tx1,pb.x)) &&
               (fminf(ty2,pb.w) > fmaxf(ty1,pb.y));
    bool inb = (mt.x-tx1>0.0f)&&(mt.y-ty1>0.0f)&&(tx2-mt.x>0.0f)&&(ty2-mt.y>0.0f);
    bool inc = fmaxf(fabsf(mt.x-txc),fabsf(mt.y-tyc)) < mt.z;
    bool ibc = inb && inc;             // ibc => inb => act (for real anchors)
    bool cand = act && (ov || ibc);
    unsigned long long bb  = __ballot(cand);
    unsigned long long bb2 = __ballot(ibc);
    if (cand){
      int pos = cnt + __popcll(bb & ((1ull << lane) - 1ull));
      if (pos < CAPW) seg[w*CAPW + pos] = a | (ibc ? (1<<15) : 0);
    }
    cnt += __popcll(bb);
    ci  += __popcll(bb2);
    pb = pbn; mt = mtn; a = a2;
  }
  if (lane == 0){ cnts_s[w] = cnt; cibc_s[w] = ci; }
  __syncthreads();

  int tibc = cibc_s[0]+cibc_s[1]+cibc_s[2]+cibc_s[3];
  bool ovf = (cnts_s[0]>CAPW)||(cnts_s[1]>CAPW)||(cnts_s[2]>CAPW)||(cnts_s[3]>CAPW);
  bool fastp = !ovf && (tibc >= 16);

  float riou[NTOP]; unsigned long long rk[NTOP];
  #pragma unroll
  for (int j=0;j<NTOP;++j){ riou[j]=0.0f; rk[j]=KSENT; }

  int cw = cnts_s[w];
  if (fastp){
    for (int j = lane; j < cw; j += 64){
      int e  = seg[w*CAPW + j];
      int a1 = e & 0x3fff;
      bool ibc = (e & (1<<15)) != 0;
      int gid = iNAP + a1;
      float4 pb2 = pbox4[gid];                      // L2-hot gather
      float iou = pair_iou(tx1,ty1,tx2,ty2, pb2.x,pb2.y,pb2.z,pb2.w);
      ins_iou(riou, iou);
      float S  = m4f[(size_t)gid*4 + 3];
      float dv = use_d ? Dc[gid] : dval_fn(sobja[gid], pred[(size_t)(iNA+a1)*PDIM + 5 + cid]);
      float c  = cost_from(S, dv, iou, ibc, true);
      ins_key(rk, key_of(c, a1));
    }
  } else {
    // exact fallback: full rescan by all 256 threads (rare)
    for (int a1 = tid; a1 < NA; a1 += 256){
      float4 mt2 = meta4[iNAP+a1];
      if (mt2.z > 0.0f){
        float4 pb2 = pbox4[iNAP+a1];
        float iou = pair_iou(tx1,ty1,tx2,ty2, pb2.x,pb2.y,pb2.z,pb2.w);
        ins_iou(riou, iou);
        bool inb = (mt2.x-tx1>0.0f)&&(mt2.y-ty1>0.0f)&&(tx2-mt2.x>0.0f)&&(ty2-mt2.y>0.0f);
        bool inc = fmaxf(fabsf(mt2.x-txc),fabsf(mt2.y-tyc)) < mt2.z;
        float dv = use_d ? Dc[iNAP+a1] : dval_fn(sobja[iNAP+a1], pred[(size_t)(iNA+a1)*PDIM + 5 + cid]);
        float c = cost_from(mt2.w, dv, iou, inb&&inc, true);
        ins_key(rk, key_of(c, a1));
      }
    }
  }

  // ---- per-wave tournament pop: 10 rounds wave-reduce + winner-pop ----
  #pragma unroll
  for (int r = 0; r < NTOP; ++r){
    float gm = riou[0];
    #pragma unroll
    for (int m = 1; m < 64; m <<= 1) gm = fmaxf(gm, __shfl_xor(gm, m));
    unsigned long long bb = __ballot(riou[0] == gm);
    int win = __ffsll(bb) - 1;
    if (lane == win){
      #pragma unroll
      for (int j=0;j<NTOP-1;++j) riou[j] = riou[j+1];
      riou[NTOP-1] = 0.0f;
    }
    if (lane == 0) wiou[w][r] = gm;
  }
  #pragma unroll
  for (int r = 0; r < NTOP; ++r){
    unsigned long long gk = rk[0];
    #pragma unroll
    for (int m = 1; m < 64; m <<= 1){
      unsigned long long o = __shfl_xor(gk, m);
      gk = (o < gk) ? o : gk;
    }
    unsigned long long bb = __ballot(rk[0] == gk);
    int win = __ffsll(bb) - 1;
    if (lane == win){
      #pragma unroll
      for (int j=0;j<NTOP-1;++j) rk[j] = rk[j+1];
      rk[NTOP-1] = KSENT;
    }
    if (lane == 0) wkey[w][r] = gk;
  }
  __syncthreads();

  // ---- wave 0: 4-way pointer merge for iou (global desc order, like jnp) ----
  int dk = 1;
  if (w == 0){
    int p0=0,p1=0,p2=0,p3=0;
    float ssum = 0.0f, rmax = 0.0f;
    #pragma unroll
    for (int r = 0; r < NTOP; ++r){
      float v0=wiou[0][p0], v1=wiou[1][p1], v2=wiou[2][p2], v3=wiou[3][p3];
      float mx = fmaxf(fmaxf(v0,v1), fmaxf(v2,v3));
      if (r == 0) rmax = mx;
      ssum += mx;
      if      (mx == v0) ++p0;
      else if (mx == v1) ++p1;
      else if (mx == v2) ++p2;
      else               ++p3;
    }
    dk = (int)ssum;
    if (dk < 1) dk = 1;
    if (lane == 0) rmax_s = rmax;
  }
  __syncthreads();

  // ---- phase 3: obj-target scatter over candidates (all 4 waves) ----
  // Bitwise-identical to the reference obj computation: same pair_iou, same
  // 1/(rmax+1e-8) divide; fmax via atomicMax over nonneg floats (uint order
  // == float order).
  float invm = 1.0f / (rmax_s + 1e-8f);
  if (fastp){
    for (int j = lane; j < cw; j += 64){
      int a1 = seg[w*CAPW + j] & 0x3fff;
      int gid = iNAP + a1;
      float4 pb2 = pbox4[gid];
      float iou = pair_iou(tx1,ty1,tx2,ty2, pb2.x,pb2.y,pb2.z,pb2.w);
      float v = iou * invm;
      if (v > 0.0f) atomicMax(&obju[gid], __float_as_uint(v));
    }
  } else {
    for (int a1 = tid; a1 < NA; a1 += 256){
      float4 mt2 = meta4[iNAP+a1];
      if (mt2.z > 0.0f){
        float4 pb2 = pbox4[iNAP+a1];
        float iou = pair_iou(tx1,ty1,tx2,ty2, pb2.x,pb2.y,pb2.z,pb2.w);
        float v = iou * invm;
        if (v > 0.0f) atomicMax(&obju[iNAP+a1], __float_as_uint(v));
      }
    }
  }

  // ---- wave 0: 4-way pointer merge for cost keys + mask scatter ----
  if (w == 0){
    int q0=0,q1=0,q2=0,q3=0;
    int myidx = 0x7fffffff;
    #pragma unroll
    for (int r = 0; r < NTOP; ++r){
      unsigned long long k0=wkey[0][q0], k1=wkey[1][q1], k2=wkey[2][q2], k3=wkey[3][q3];
      unsigned long long mn = k0;
      mn = (k1 < mn) ? k1 : mn;
      mn = (k2 < mn) ? k2 : mn;
      mn = (k3 < mn) ? k3 : mn;
      if (lane == r) myidx = (int)(mn & 0xFFFFFFFFull);
      if      (mn == k0) ++q0;
      else if (mn == k1) ++q1;
      else if (mn == k2) ++q2;
      else               ++q3;
    }

    if (lane < NTOP && lane < dk){
      int a1 = myidx;
      if (a1 >= 0 && a1 < NA){     // sentinel idx = 0x7FFFFFFF skipped
        atomicOr(&mask[(size_t)(iNAP + a1)*2 + (t>>6)], 1ull << (t & 63));
      }
    }
  }
}

// ---------- Kernel 2: per-anchor resolution + loss partial sums --------------
// Conflicted anchors (cnt>1) resolved by a WAVE-COOPERATIVE argmin: one wave
// per conflicted anchor, lane l evaluates targets l and l+64 (2 independent
// gathers -> ONE memory latency, not an 8-deep chain), then a 6-step u64
// key min-reduce (cost bits | t) == first-min argmin, bit-exact vs ref.
// All independent loads hoisted to kernel top (single latency for epilogue).
__global__ __launch_bounds__(256) void k2_peranchor(
    const float* __restrict__ pred,
    const float4* __restrict__ pbox4, const float4* __restrict__ meta4,
    const float* __restrict__ obja, const float* __restrict__ sobja,
    const float* __restrict__ S0a,
    const float* __restrict__ D, int use_d,
    const float* __restrict__ target,
    const unsigned int* __restrict__ obju, const unsigned long long* __restrict__ mask,
    float* __restrict__ acc)
{
  __shared__ float4 tb4[NT];
  __shared__ int    tcid[NT];
  __shared__ int    cl[256];     // compacted conflicted-anchor thread ids
  __shared__ int    bt_s[256];   // per-anchor argmin result
  __shared__ int    ncl;
  __shared__ float4 part[4];     // per-wave partial sums

  int i  = blockIdx.x / BPI2;
  int b  = blockIdx.x - i*BPI2;
  int tid = threadIdx.x, lane = tid & 63, w = tid >> 6;
  int a  = b*256 + tid;                // 0..NAP-1
  int gid = i*NAP + a;

  if (tid < NT){
    const float* tg = target + (i*NT + tid)*6;
    tcid[tid] = (int)tg[1];
    tb4[tid]  = make_float4(tg[2],tg[3],tg[4],tg[5]);
  }
  if (tid == 0) ncl = 0;

  // ---- hoisted independent loads: all in flight together (one latency) ----
  bool valid = (a < NA);
  float4 pb = pbox4[gid];              // pads: zero box (k0-initialized)
  float4 mt = meta4[gid];              // pads: z=-1
  unsigned long long m0=0, m1=0;
  if (valid){ m0 = mask[(size_t)gid*2]; m1 = mask[(size_t)gid*2+1]; }
  float bestv = __uint_as_float(obju[gid]);  // max_t iou*invm (k1-scattered)
  float olv   = obja[gid];
  float S0v   = S0a[gid];

  bool ib = valid && (mt.z > 0.0f);
  float px1=pb.x, py1=pb.y, px2=pb.z, py2=pb.w;
  int cnt = __popcll(m0) + __popcll(m1);

  __syncthreads();   // tb4/tcid/ncl ready

  // ---- compact conflicted anchors into cl[] (per-wave ballot + LDS base) ----
  bool myc = (cnt > 1);
  unsigned long long cb = __ballot(myc);
  int nb = __popcll(cb);
  int base = 0;
  if (lane == 0 && nb) base = atomicAdd(&ncl, nb);
  base = __shfl(base, 0);
  if (myc) cl[base + __popcll(cb & ((1ull << lane) - 1ull))] = tid;
  __syncthreads();

  // ---- worker pass: one WAVE per conflicted anchor, 2 targets per lane ----
  int tot = ncl;
  for (int ci = w; ci < tot; ci += 4){
    int aidx = cl[ci];
    int a2g  = b*256 + aidx;
    int gid2 = i*NAP + a2g;
    float4 pb2 = pbox4[gid2];          // uniform across wave (broadcast)
    float4 mt2 = meta4[gid2];
    bool ib2 = (mt2.z > 0.0f);
    float rc2 = fabsf(mt2.z);
    float Sg  = mt2.w;
    float sobj = use_d ? 0.0f : sobja[gid2];
    size_t pbase = (size_t)(i*NA + a2g)*PDIM;

    int ta = lane, tb = lane + 64;
    // both gathers issued before use -> one latency
    float dva = use_d ? D[(size_t)tcid[ta]*BAPC + gid2]
                      : dval_fn(sobj, pred[pbase + 5 + tcid[ta]]);
    float dvb = use_d ? D[(size_t)tcid[tb]*BAPC + gid2]
                      : dval_fn(sobj, pred[pbase + 5 + tcid[tb]]);

    float4 Ta = tb4[ta];
    float ioua = ib2 ? pair_iou(Ta.x,Ta.y,Ta.z,Ta.w,pb2.x,pb2.y,pb2.z,pb2.w) : 0.0f;
    bool inba = (mt2.x-Ta.x>0.0f)&&(mt2.y-Ta.y>0.0f)&&(Ta.z-mt2.x>0.0f)&&(Ta.w-mt2.y>0.0f);
    float txa=(Ta.x+Ta.z)*0.5f, tya=(Ta.y+Ta.w)*0.5f;
    bool inca = fmaxf(fabsf(mt2.x-txa),fabsf(mt2.y-tya)) < rc2;
    unsigned long long ka = key_of(cost_from(Sg, dva, ioua, inba&&inca, ib2), ta);

    float4 Tb = tb4[tb];
    float ioub = ib2 ? pair_iou(Tb.x,Tb.y,Tb.z,Tb.w,pb2.x,pb2.y,pb2.z,pb2.w) : 0.0f;
    bool inbb = (mt2.x-Tb.x>0.0f)&&(mt2.y-Tb.y>0.0f)&&(Tb.z-mt2.x>0.0f)&&(Tb.w-mt2.y>0.0f);
    float txb=(Tb.x+Tb.z)*0.5f, tyb=(Tb.y+Tb.w)*0.5f;
    bool incb = fmaxf(fabsf(mt2.x-txb),fabsf(mt2.y-tyb)) < rc2;
    unsigned long long kb = key_of(cost_from(Sg, dvb, ioub, inbb&&incb, ib2), tb);

    unsigned long long mn = (kb < ka) ? kb : ka;
    #pragma unroll
    for (int m = 1; m < 64; m <<= 1){
      unsigned long long o = __shfl_xor(mn, m);
      mn = (o < mn) ? o : mn;
    }
    if (lane == 0) bt_s[aidx] = (int)(mn & 0xFFFFFFFFull);
  }
  __syncthreads();

  // ---- epilogue: per-anchor losses (all data already in registers) ----
  float m=0.0f, vbox=0.0f, vobj=0.0f, vcls=0.0f;
  if (valid){
    float obj_t = ib ? fminf(fmaxf(bestv,0.0f),1.0f) : 0.0f;
    vobj = bce_fast(olv, obj_t);

    int tp = 0; bool mpv = false;
    if (cnt > 1){ tp = bt_s[tid]; mpv = true; }
    else if (cnt == 1){
      tp = m0 ? (__ffsll(m0)-1) : (64 + __ffsll(m1)-1);
      mpv = true;
    }

    if (mpv){
      m = 1.0f;
      float4 T = tb4[tp];
      float x1=T.x, y1=T.y, x2=T.z, y2=T.w;
      float w2 = fmaxf(fminf(px2,x2)-fmaxf(px1,x1),0.0f);
      float h2 = fmaxf(fminf(py2,y2)-fmaxf(py1,y1),0.0f);
      float inter = w2*h2;
      float wp=px2-px1, hp=py2-py1, wt=x2-x1, ht=y2-y1;
      float iou = inter/(wp*hp + wt*ht - inter + 1e-8f);
      float cw = fmaxf(px2,x2)-fminf(px1,x1);
      float ch = fmaxf(py2,y2)-fminf(py1,y1);
      float c2 = cw*cw + ch*ch + 1e-8f;
      float dx = (px1+px2)-(x1+x2), dy = (py1+py2)-(y1+y2);
      float rho2 = (dx*dx + dy*dy)/4.0f;
      float da = atanf(wt/(ht+1e-8f)) - atanf(wp/(hp+1e-8f));
      float v  = 0.4052847345693511f * da * da;   // 4/pi^2
      float alpha = v/(1.0f - iou + v + 1e-8f);
      vbox = 1.0f - (iou - rho2/c2 - alpha*v);

      int cc = tcid[tp];
      float xcc = pred[(size_t)(i*NA + a)*PDIM + 5 + cc];
      vcls = (S0v - xcc) * (1.0f/80.0f);   // sum_c bce(x_c, onehot) = S0 - x_cc
    }
  }

  // wave reduce -> LDS -> single atomic quad per BLOCK (528 vs 2112 quads)
  #pragma unroll
  for (int off=32; off>0; off>>=1){
    m    += __shfl_down(m, off);
    vbox += __shfl_down(vbox, off);
    vobj += __shfl_down(vobj, off);
    vcls += __shfl_down(vcls, off);
  }
  if (lane == 0) part[w] = make_float4(m, vbox, vobj, vcls);
  __syncthreads();
  if (tid == 0){
    float4 s0 = part[0], s1 = part[1], s2 = part[2], s3 = part[3];
    float4 s = make_float4(s0.x+s1.x+s2.x+s3.x, s0.y+s1.y+s2.y+s3.y,
                           s0.z+s1.z+s2.z+s3.z, s0.w+s1.w+s2.w+s3.w);
    int slot = (blockIdx.x & 63)*4;
    atomicAdd(&acc[slot+0], s.x);
    atomicAdd(&acc[slot+1], s.y);
    atomicAdd(&acc[slot+2], s.z);
    atomicAdd(&acc[slot+3], s.w);
  }
}

// ---------------- Kernel 3: finalize (reduce 64 accumulator slots) -----------
__global__ void k3_final(const float* __restrict__ acc, float* __restrict__ out){
  int l = threadIdx.x;   // 64 threads
  float4 v = ((const float4*)acc)[l];
  #pragma unroll
  for (int off=32; off>0; off>>=1){
    v.x += __shfl_down(v.x, off);
    v.y += __shfl_down(v.y, off);
    v.z += __shfl_down(v.z, off);
    v.w += __shfl_down(v.w, off);
  }
  if (l == 0){
    float n    = fmaxf(v.x, 1.0f);
    float lbox = 0.05f * v.y / n;
    float lobj = v.z / (float)(NB*NA);
    float lcls = 0.5f  * v.w / n;
    out[0] = lbox + lobj + lcls;
    out[1] = lbox; out[2] = lobj; out[3] = lcls;
  }
}

extern "C" void kernel_launch(void* const* d_in, const int* in_sizes, int n_in,
                              void* d_out, int out_size, void* d_ws, size_t ws_size,
                              hipStream_t stream) {
  const float* pred    = (const float*)d_in[0];
  const float* target  = (const float*)d_in[1];
  const float* grid    = (const float*)d_in[2];
  const float* stridev = (const float*)d_in[3];
  float* out = (float*)d_out;

  char* ws = (char*)d_ws;

  size_t off = 0;
  unsigned long long* mask = (unsigned long long*)(ws + off); off += BAPC*16;
  float* acc    = (float*)(ws + off); off += 64*4*4;
  float4* pbox4 = (float4*)(ws + off); off += BAPC*16;
  float4* meta4 = (float4*)(ws + off); off += BAPC*16;
  float* obja   = (float*)(ws + off); off += BAPC*4;
  float* sobja  = (float*)(ws + off); off += BAPC*4;
  float* S0a    = (float*)(ws + off); off += BAPC*4;
  unsigned int* obju = (unsigned int*)(ws + off); off += BAPC*4;
  float* D      = (float*)(ws + off);
  const size_t need_d = off + (size_t)NCLS*BAPC*4;
  int use_d = (ws_size >= need_d) ? 1 : 0;

  // mask+acc+obju zeroed inside k0 (no memset dispatch)
  k0_precompute<<<NB*BPI, 256, 0, stream>>>(pred, target, grid, stridev,
                                            pbox4, meta4, obja, sobja, S0a, D, use_d,
                                            mask, obju, acc);
  k1_pertarget <<<NB*NT,  256, 0, stream>>>(pbox4, meta4, D, use_d,
                                            sobja, pred, target, obju, mask);
  k2_peranchor <<<NB*BPI2, 256, 0, stream>>>(pred, pbox4, meta4, obja, sobja, S0a,
                                             D, use_d, target, obju, mask, acc);
  k3_final     <<<1, 64, 0, stream>>>(acc, out);
}

// Round 6
// 152.163 us; speedup vs baseline: 1.5172x; 1.0532x over previous
//
#include <hip/hip_runtime.h>
#include <cfloat>

#pragma clang fp contract(off)

#define NCLS 80
#define PDIM 85
#define NA   8400
#define NAP  8448          // padded per-image anchor stride = 33*256 (BPI*64)
#define NB   16
#define NT   128
#define NTOP 10
#define APB  64      // anchors per k0 block == group size
#define BPI  132     // ceil(NA/64) ; BPI*64 == NAP ; also #groups per image
#define BPI2 33      // k2: 256 anchors per block ; BPI2*256 == NAP
#define LN2  0.6931471805599453f
#define CAPW 768     // per-wave compaction capacity (int entries; worst case ~300)

#define BAPC ((size_t)NB*NAP)

#define KSENT 0xFFFFFFFF7FFFFFFFull   // sentinel key: huge cost, idx 0x7FFFFFFF

// fast native sigmoid: rcp(1+exp(-x)).
__device__ __forceinline__ float sigm_fast(float x){
  float e = __expf(-x);
  return __builtin_amdgcn_rcpf(1.0f + e);
}

// fast bce (value path only)
__device__ __forceinline__ float bce_fast(float x, float t){
  float ax = fabsf(x);
  float e  = __expf(-ax);
  return fmaxf(x,0.0f) - x*t + LN2*__builtin_amdgcn_logf(1.0f + e);
}

// Fast-rcp IoU. Used identically in k1 (topk + obj re-walk) and k2 -> consistent.
__device__ __forceinline__ float pair_iou(float tx1,float ty1,float tx2,float ty2,
                                          float px1,float py1,float px2,float py2){
  float w = fminf(tx2,px2) - fmaxf(tx1,px1);
  float h = fminf(ty2,py2) - fmaxf(ty1,py1);
  w = fmaxf(w,0.0f); h = fmaxf(h,0.0f);
  float inter = w*h;
  float at = fmaxf(tx2-tx1,0.0f)*fmaxf(ty2-ty1,0.0f);
  float ap = fmaxf(px2-px1,0.0f)*fmaxf(py2-py1,0.0f);
  float den = at+ap-inter+1e-8f;
  return inter * __builtin_amdgcn_rcpf(den);
}

// dval fallback (use_d==0 only; normally D table is used)
__device__ __forceinline__ float dval_fn(float sobj, float lg){
  float ln_sobj = LN2*__builtin_amdgcn_logf(sobj);
  float e = __expf(-fabsf(lg));
  float L = LN2*__builtin_amdgcn_logf(1.0f + e);
  float ln_sc = -(fmaxf(-lg,0.0f) + L);
  float lph = 0.5f*(ln_sobj + ln_sc);
  float p = __expf(lph);
  float lp = fmaxf(lph, -100.0f);
  float l1 = fmaxf(LN2*__builtin_amdgcn_logf(fmaxf(1.0f - p, 0.0f)), -100.0f);
  return lp - l1;
}

// Selection-critical: identical in k1 top-k and k2 argmin (same inline, contract off).
__device__ __forceinline__ float cost_from(float S, float dval, float iou, bool ibc, bool ib){
  float iouc = -LN2 * __builtin_amdgcn_logf(iou + 1e-8f);
  float clsc = -(S + dval);
  float c = clsc + 3.0f*iouc;
  c = c + (ibc ? 0.0f : 100000.0f);
  c = c + (ib  ? 0.0f : 1000000000.0f);
  return c;
}

// sortable u64 key: ascending key order == ascending (cost, idx) lexicographic
__device__ __forceinline__ unsigned long long key_of(float c, int idx){
  unsigned int u = __float_as_uint(c);
  u ^= (u & 0x80000000u) ? 0xFFFFFFFFu : 0x80000000u;
  return ((unsigned long long)u << 32) | (unsigned int)idx;
}

// sorted-insert helpers (branchless unrolled shift; order-independent)
__device__ __forceinline__ void ins_iou(float* riou, float iou){
  if (iou > riou[NTOP-1]){
    #pragma unroll
    for (int j = NTOP-1; j >= 1; --j){
      bool gj  = iou > riou[j];
      bool gj1 = iou > riou[j-1];
      riou[j] = gj ? (gj1 ? riou[j-1] : iou) : riou[j];
    }
    riou[0] = (iou > riou[0]) ? iou : riou[0];
  }
}
__device__ __forceinline__ void ins_key(unsigned long long* rk, unsigned long long key){
  if (key < rk[NTOP-1]){
    #pragma unroll
    for (int j = NTOP-1; j >= 1; --j){
      bool bj  = key < rk[j];
      bool bj1 = key < rk[j-1];
      rk[j] = bj ? (bj1 ? rk[j-1] : key) : rk[j];
    }
    rk[0] = (key < rk[0]) ? key : rk[0];
  }
}

// ---------------- Kernel 0: transpose + per-anchor precompute ----------------
// Additionally emits per-64-anchor-group conservative AABBs (over in-box
// anchors only): [0] pred-box hull, [1] center hull, [2] center+-rc hull.
// Empty group (no ib anchors) -> +-INF hull -> always culled in k1.
__global__ __launch_bounds__(256) void k0_precompute(
    const float* __restrict__ pred, const float* __restrict__ target,
    const float* __restrict__ grid, const float* __restrict__ stridev,
    float4* __restrict__ pbox4, float4* __restrict__ meta4,
    float* __restrict__ obja, float* __restrict__ sobja,
    float* __restrict__ S0a, float* __restrict__ D, int use_d,
    unsigned long long* __restrict__ mask, unsigned int* __restrict__ obju,
    float4* __restrict__ gaabb, float* __restrict__ acc)
{
  __shared__ float  tile[APB*PDIM];   // [a][c], stride 85 (odd -> conflict-free)
  __shared__ float4 tb4s[NT];
  __shared__ float  ps_s[4][APB];
  __shared__ float  ps0_s[4][APB];
  __shared__ int    ib_s[4][APB];

  int i  = blockIdx.x / BPI;
  int b  = blockIdx.x % BPI;
  int c0 = b*APB;
  int n  = NA - c0; if (n > APB) n = APB;
  int tid = threadIdx.x;

  if (blockIdx.x == 0) acc[tid] = 0.0f;   // 256 slots

  const float* src = pred + ((size_t)i*NA + c0)*PDIM;
  int tot = n*PDIM;
  for (int idx = tid; idx < tot; idx += 256) tile[idx] = src[idx];
  for (int idx = tid; idx < NT; idx += 256){
    const float* tg = target + (i*NT + idx)*6;
    tb4s[idx] = make_float4(tg[2],tg[3],tg[4],tg[5]);
  }
  __syncthreads();

  int al = tid & 63, cg = tid >> 6;
  if (al < n){
    int gid = i*NAP + c0 + al;
    // softplus identity: ln sigm(x) = -(max(-x,0)+L), L = ln(1+exp(-|x|))
    float x4 = tile[al*PDIM+4];
    float e4 = __expf(-fabsf(x4));
    float L4 = LN2*__builtin_amdgcn_logf(1.0f + e4);
    float ln_sobj = -(fmaxf(-x4,0.0f) + L4);
    float ps = 0.0f, ps0 = 0.0f;
    #pragma unroll 4
    for (int k = 0; k < 20; ++k){
      int c = cg*20 + k;
      float x  = tile[al*PDIM+5+c];
      float e  = __expf(-fabsf(x));
      float L  = LN2*__builtin_amdgcn_logf(1.0f + e);
      float ln_sc = -(fmaxf(-x,0.0f) + L);
      float lph = 0.5f*(ln_sobj + ln_sc);     // ln p = 0.5 ln(sobj*sc)
      float p   = __expf(lph);
      float lp  = fmaxf(lph, -100.0f);
      float l1  = fmaxf(LN2*__builtin_amdgcn_logf(fmaxf(1.0f - p, 0.0f)), -100.0f);
      ps  += l1;
      if (use_d) D[(size_t)c*BAPC + gid] = lp - l1;
      ps0 += fmaxf(x,0.0f) + L;               // bce(x,0) reuses L
    }
    ps_s[cg][al] = ps; ps0_s[cg][al] = ps0;

    int ga = c0 + al;
    float xg = grid[2*ga], yg = grid[2*ga+1], sv = stridev[ga];
    float xc = (xg + 0.5f)*sv, yc = (yg + 0.5f)*sv;
    float rc = 2.5f*sv;
    bool ibp = false;
    #pragma unroll 4
    for (int t = cg*32; t < cg*32+32; ++t){
      float4 T = tb4s[t];
      bool inb = (xc-T.x>0.0f)&&(yc-T.y>0.0f)&&(T.z-xc>0.0f)&&(T.w-yc>0.0f);
      float txc=(T.x+T.z)*0.5f, tyc=(T.y+T.w)*0.5f;
      bool inc = fmaxf(fabsf(xc-txc),fabsf(yc-tyc)) < rc;
      ibp = ibp || inb || inc;
    }
    ib_s[cg][al] = ibp ? 1 : 0;
  }
  __syncthreads();

  if (tid < APB){            // wave 0 only: all 64 lanes active
    int a = tid;
    bool real = (a < n);
    int gid = i*NAP + c0 + a;
    float x1=0,y1=0,x2=0,y2=0,xc=0,yc=0,rc=0;
    bool ib = false;

    if (real){
      float s  = ps_s[0][a]  + ps_s[1][a]  + ps_s[2][a]  + ps_s[3][a];
      float s0 = ps0_s[0][a] + ps0_s[1][a] + ps0_s[2][a] + ps0_s[3][a];
      ib  = (ib_s[0][a] | ib_s[1][a] | ib_s[2][a] | ib_s[3][a]) != 0;

      x1 = tile[a*PDIM+0]; y1 = tile[a*PDIM+1];
      x2 = tile[a*PDIM+2]; y2 = tile[a*PDIM+3];
      float ol = tile[a*PDIM+4];
      pbox4[gid] = make_float4(x1,y1,x2,y2);
      obja[gid]  = ol;
      sobja[gid] = sigm_fast(ol);
      S0a[gid]   = s0;
      mask[(size_t)gid*2]   = 0ull;   // replaces host-side memset
      mask[(size_t)gid*2+1] = 0ull;
      obju[gid] = 0u;                 // obj-target accumulator (f32-as-u32, >=0)

      int ga = c0 + a;
      float xg = grid[2*ga], yg = grid[2*ga+1], sv = stridev[ga];
      xc = (xg + 0.5f)*sv; yc = (yg + 0.5f)*sv;
      rc = 2.5f*sv;
      meta4[gid] = make_float4(xc, yc, ib ? rc : -rc, s);  // sign(z) = in_box
    } else {
      // pad anchors (only last block per image, n=16): never active in k1/k2
      meta4[gid] = make_float4(0.0f, 0.0f, -1.0f, 0.0f);
      pbox4[gid] = make_float4(0.0f, 0.0f, 0.0f, 0.0f);
      obju[gid]  = 0u;
    }

    // ---- group AABB reduction over in-box anchors (wave 0, 12 values) ----
    bool iv = real && ib;
    float bx1 = iv ? x1 : FLT_MAX,  by1 = iv ? y1 : FLT_MAX;
    float bx2 = iv ? x2 : -FLT_MAX, by2 = iv ? y2 : -FLT_MAX;
    float cx1 = iv ? xc : FLT_MAX,  cy1 = iv ? yc : FLT_MAX;
    float cx2 = iv ? xc : -FLT_MAX, cy2 = iv ? yc : -FLT_MAX;
    float rx1 = iv ? xc-rc : FLT_MAX,  ry1 = iv ? yc-rc : FLT_MAX;
    float rx2 = iv ? xc+rc : -FLT_MAX, ry2 = iv ? yc+rc : -FLT_MAX;
    #pragma unroll
    for (int off = 32; off > 0; off >>= 1){
      bx1 = fminf(bx1, __shfl_xor(bx1, off));
      by1 = fminf(by1, __shfl_xor(by1, off));
      bx2 = fmaxf(bx2, __shfl_xor(bx2, off));
      by2 = fmaxf(by2, __shfl_xor(by2, off));
      cx1 = fminf(cx1, __shfl_xor(cx1, off));
      cy1 = fminf(cy1, __shfl_xor(cy1, off));
      cx2 = fmaxf(cx2, __shfl_xor(cx2, off));
      cy2 = fmaxf(cy2, __shfl_xor(cy2, off));
      rx1 = fminf(rx1, __shfl_xor(rx1, off));
      ry1 = fminf(ry1, __shfl_xor(ry1, off));
      rx2 = fmaxf(rx2, __shfl_xor(rx2, off));
      ry2 = fmaxf(ry2, __shfl_xor(ry2, off));
    }
    if (tid == 0){
      size_t gb = (size_t)(i*BPI + b)*3;
      gaabb[gb+0] = make_float4(bx1,by1,bx2,by2);
      gaabb[gb+1] = make_float4(cx1,cy1,cx2,cy2);
      gaabb[gb+2] = make_float4(rx1,ry1,rx2,ry2);
    }
  }
}

// ---- Kernel 1: per-target group-culled scan + register tournament top-k -----
// Phase 0 (new): conservative group-AABB cull -- wave w tests its 33 groups
// (G = w+4k) with one ballot; the anchor scan then visits only surviving
// groups via a wave-uniform ffs loop. Skipped groups have zero candidates
// (strict-inequality containment proof), so seg/cnt are bit-identical.
// Phase 1: cheap candidacy test (7-op overlap == iou>0 exactly) + compaction.
// Phase 2: full IoU/cost over candidates. Phase 3: obj-target atomicMax scatter.
__global__ __launch_bounds__(256) void k1_pertarget(
    const float4* __restrict__ pbox4, const float4* __restrict__ meta4,
    const float* __restrict__ D, int use_d,
    const float* __restrict__ sobja, const float* __restrict__ pred,
    const float* __restrict__ target, const float4* __restrict__ gaabb,
    unsigned int* __restrict__ obju, unsigned long long* __restrict__ mask)
{
  __shared__ int   seg[4*CAPW];                      // 12 KB (index | ibc<<15)
  __shared__ int   cnts_s[4], cibc_s[4];
  __shared__ float wiou[4][NTOP];                    // per-wave desc iou
  __shared__ unsigned long long wkey[4][NTOP];       // per-wave asc cost keys
  __shared__ float rmax_s;

  int tid = threadIdx.x, lane = tid & 63, w = tid >> 6;
  int g = blockIdx.x;
  int i = g / NT, t = g - i*NT;
  int iNAP = i*NAP;
  int iNA  = i*NA;
  const float* m4f = (const float*)meta4;

  const float* tg = target + (size_t)g*6;
  int   cid = (int)tg[1];
  float tx1 = tg[2], ty1 = tg[3], tx2 = tg[4], ty2 = tg[5];
  float txc = (tx1+tx2)*0.5f, tyc = (ty1+ty2)*0.5f;
  const float* Dc = use_d ? (D + (size_t)cid*BAPC) : nullptr;

  // ---- phase 0: group cull. lane k<33 tests group G = w+4k ----
  bool sv = false;
  if (lane < 33){
    size_t gb = (size_t)(i*BPI + (w + 4*lane))*3;
    float4 gbb = gaabb[gb+0];
    float4 gcc = gaabb[gb+1];
    float4 grr = gaabb[gb+2];
    bool ovg  = (fminf(tx2,gbb.z) > fmaxf(tx1,gbb.x)) &&
                (fminf(ty2,gbb.w) > fmaxf(ty1,gbb.y));
    bool inbg = (gcc.z > tx1) && (gcc.x < tx2) && (gcc.w > ty1) && (gcc.y < ty2);
    bool incg = (txc > grr.x) && (txc < grr.z) && (tyc > grr.y) && (tyc < grr.w);
    sv = ovg || (inbg && incg);
  }
  unsigned long long gmsk = __ballot(sv);   // wave-uniform, bits 0..32

  // ---- phase 1: culled scan, per-wave compaction (no IoU) ----
  int cnt = 0, ci = 0;
  while (gmsk){
    int k = __ffsll(gmsk) - 1; gmsk &= gmsk - 1;   // ascending k: order kept
    int a = w*64 + k*256 + lane;
    float4 pb = pbox4[iNAP+a];
    float4 mt = meta4[iNAP+a];

    bool act = (mt.z > 0.0f);          // in_box-any; pads have z=-1
    // strict overlap == (iou > 0): inter>0 iff both extents positive
    bool ov  = (fminf(tx2,pb.z) > fmaxf(tx1,pb.x)) &&
               (fminf(ty2,pb.w) > fmaxf(ty1,pb.y));
    bool inb = (mt.x-tx1>0.0f)&&(mt.y-ty1>0.0f)&&(tx2-mt.x>0.0f)&&(ty2-mt.y>0.0f);
    bool inc = fmaxf(fabsf(mt.x-txc),fabsf(mt.y-tyc)) < mt.z;
    bool ibc = inb && inc;             // ibc => inb => act (for real anchors)
    bool cand = act && (ov || ibc);
    unsigned long long bb  = __ballot(cand);
    unsigned long long bb2 = __ballot(ibc);
    if (cand){
      int pos = cnt + __popcll(bb & ((1ull << lane) - 1ull));
      if (pos < CAPW) seg[w*CAPW + pos] = a | (ibc ? (1<<15) : 0);
    }
    cnt += __popcll(bb);
    ci  += __popcll(bb2);
  }
  if (lane == 0){ cnts_s[w] = cnt; cibc_s[w] = ci; }
  __syncthreads();

  int tibc = cibc_s[0]+cibc_s[1]+cibc_s[2]+cibc_s[3];
  bool ovf = (cnts_s[0]>CAPW)||(cnts_s[1]>CAPW)||(cnts_s[2]>CAPW)||(cnts_s[3]>CAPW);
  bool fastp = !ovf && (tibc >= 16);

  float riou[NTOP]; unsigned long long rk[NTOP];
  #pragma unroll
  for (int j=0;j<NTOP;++j){ riou[j]=0.0f; rk[j]=KSENT; }

  int cw = cnts_s[w];
  if (fastp){
    for (int j = lane; j < cw; j += 64){
      int e  = seg[w*CAPW + j];
      int a1 = e & 0x3fff;
      bool ibc = (e & (1<<15)) != 0;
      int gid = iNAP + a1;
      float4 pb2 = pbox4[gid];                      // L2-hot gather
      float iou = pair_iou(tx1,ty1,tx2,ty2, pb2.x,pb2.y,pb2.z,pb2.w);
      ins_iou(riou, iou);
      float S  = m4f[(size_t)gid*4 + 3];
      float dv = use_d ? Dc[gid] : dval_fn(sobja[gid], pred[(size_t)(iNA+a1)*PDIM + 5 + cid]);
      float c  = cost_from(S, dv, iou, ibc, true);
      ins_key(rk, key_of(c, a1));
    }
  } else {
    // exact fallback: full rescan by all 256 threads (rare)
    for (int a1 = tid; a1 < NA; a1 += 256){
      float4 mt2 = meta4[iNAP+a1];
      if (mt2.z > 0.0f){
        float4 pb2 = pbox4[iNAP+a1];
        float iou = pair_iou(tx1,ty1,tx2,ty2, pb2.x,pb2.y,pb2.z,pb2.w);
        ins_iou(riou, iou);
        bool inb = (mt2.x-tx1>0.0f)&&(mt2.y-ty1>0.0f)&&(tx2-mt2.x>0.0f)&&(ty2-mt2.y>0.0f);
        bool inc = fmaxf(fabsf(mt2.x-txc),fabsf(mt2.y-tyc)) < mt2.z;
        float dv = use_d ? Dc[iNAP+a1] : dval_fn(sobja[iNAP+a1], pred[(size_t)(iNA+a1)*PDIM + 5 + cid]);
        float c = cost_from(mt2.w, dv, iou, inb&&inc, true);
        ins_key(rk, key_of(c, a1));
      }
    }
  }

  // ---- per-wave tournament pop: 10 rounds wave-reduce + winner-pop ----
  #pragma unroll
  for (int r = 0; r < NTOP; ++r){
    float gm = riou[0];
    #pragma unroll
    for (int m = 1; m < 64; m <<= 1) gm = fmaxf(gm, __shfl_xor(gm, m));
    unsigned long long bb = __ballot(riou[0] == gm);   // dup values possible
    int win = __ffsll(bb) - 1;
    if (lane == win){
      #pragma unroll
      for (int j=0;j<NTOP-1;++j) riou[j] = riou[j+1];
      riou[NTOP-1] = 0.0f;
    }
    if (lane == 0) wiou[w][r] = gm;
  }
  #pragma unroll
  for (int r = 0; r < NTOP; ++r){
    unsigned long long gk = rk[0];
    #pragma unroll
    for (int m = 1; m < 64; m <<= 1){
      unsigned long long o = __shfl_xor(gk, m);
      gk = (o < gk) ? o : gk;
    }
    // keys unique (idx embedded) -> winner self-identifies, no ballot.
    // all-sentinel round: every lane shifts its sentinel list (harmless).
    if (rk[0] == gk){
      #pragma unroll
      for (int j=0;j<NTOP-1;++j) rk[j] = rk[j+1];
      rk[NTOP-1] = KSENT;
    }
    if (lane == 0) wkey[w][r] = gk;
  }
  __syncthreads();

  // ---- wave 0: 4-way pointer merge for iou (global desc order, like jnp) ----
  int dk = 1;
  if (w == 0){
    int p0=0,p1=0,p2=0,p3=0;
    float ssum = 0.0f, rmax = 0.0f;
    #pragma unroll
    for (int r = 0; r < NTOP; ++r){
      float v0=wiou[0][p0], v1=wiou[1][p1], v2=wiou[2][p2], v3=wiou[3][p3];
      float mx = fmaxf(fmaxf(v0,v1), fmaxf(v2,v3));
      if (r == 0) rmax = mx;
      ssum += mx;
      if      (mx == v0) ++p0;
      else if (mx == v1) ++p1;
      else if (mx == v2) ++p2;
      else               ++p3;
    }
    dk = (int)ssum;
    if (dk < 1) dk = 1;
    if (lane == 0) rmax_s = rmax;
  }
  __syncthreads();

  // ---- phase 3: obj-target scatter over candidates (all 4 waves) ----
  // Bitwise-identical to the reference obj computation: same pair_iou, same
  // 1/(rmax+1e-8) divide; fmax via atomicMax over nonneg floats (uint order
  // == float order).
  float invm = 1.0f / (rmax_s + 1e-8f);
  if (fastp){
    for (int j = lane; j < cw; j += 64){
      int a1 = seg[w*CAPW + j] & 0x3fff;
      int gid = iNAP + a1;
      float4 pb2 = pbox4[gid];
      float iou = pair_iou(tx1,ty1,tx2,ty2, pb2.x,pb2.y,pb2.z,pb2.w);
      float v = iou * invm;
      if (v > 0.0f) atomicMax(&obju[gid], __float_as_uint(v));
    }
  } else {
    for (int a1 = tid; a1 < NA; a1 += 256){
      float4 mt2 = meta4[iNAP+a1];
      if (mt2.z > 0.0f){
        float4 pb2 = pbox4[iNAP+a1];
        float iou = pair_iou(tx1,ty1,tx2,ty2, pb2.x,pb2.y,pb2.z,pb2.w);
        float v = iou * invm;
        if (v > 0.0f) atomicMax(&obju[iNAP+a1], __float_as_uint(v));
      }
    }
  }

  // ---- wave 0: 4-way pointer merge for cost keys + mask scatter ----
  if (w == 0){
    int q0=0,q1=0,q2=0,q3=0;
    int myidx = 0x7fffffff;
    #pragma unroll
    for (int r = 0; r < NTOP; ++r){
      unsigned long long k0=wkey[0][q0], k1=wkey[1][q1], k2=wkey[2][q2], k3=wkey[3][q3];
      unsigned long long mn = k0;
      mn = (k1 < mn) ? k1 : mn;
      mn = (k2 < mn) ? k2 : mn;
      mn = (k3 < mn) ? k3 : mn;
      if (lane == r) myidx = (int)(mn & 0xFFFFFFFFull);
      if      (mn == k0) ++q0;
      else if (mn == k1) ++q1;
      else if (mn == k2) ++q2;
      else               ++q3;
    }

    if (lane < NTOP && lane < dk){
      int a1 = myidx;
      if (a1 >= 0 && a1 < NA){     // sentinel idx = 0x7FFFFFFF skipped
        atomicOr(&mask[(size_t)(iNAP + a1)*2 + (t>>6)], 1ull << (t & 63));
      }
    }
  }
}

// ---------- Kernel 2: per-anchor resolution + loss partial sums --------------
// Conflicted anchors (cnt>1) resolved by a WAVE-COOPERATIVE argmin: one wave
// per conflicted anchor, lane l evaluates targets l and l+64 (2 independent
// gathers -> ONE memory latency), then a 6-step u64 key min-reduce
// (cost bits | t) == first-min argmin, bit-exact vs ref.
__global__ __launch_bounds__(256) void k2_peranchor(
    const float* __restrict__ pred,
    const float4* __restrict__ pbox4, const float4* __restrict__ meta4,
    const float* __restrict__ obja, const float* __restrict__ sobja,
    const float* __restrict__ S0a,
    const float* __restrict__ D, int use_d,
    const float* __restrict__ target,
    const unsigned int* __restrict__ obju, const unsigned long long* __restrict__ mask,
    float* __restrict__ acc)
{
  __shared__ float4 tb4[NT];
  __shared__ int    tcid[NT];
  __shared__ int    cl[256];     // compacted conflicted-anchor thread ids
  __shared__ int    bt_s[256];   // per-anchor argmin result
  __shared__ int    ncl;
  __shared__ float4 part[4];     // per-wave partial sums

  int i  = blockIdx.x / BPI2;
  int b  = blockIdx.x - i*BPI2;
  int tid = threadIdx.x, lane = tid & 63, w = tid >> 6;
  int a  = b*256 + tid;                // 0..NAP-1
  int gid = i*NAP + a;

  if (tid < NT){
    const float* tg = target + (i*NT + tid)*6;
    tcid[tid] = (int)tg[1];
    tb4[tid]  = make_float4(tg[2],tg[3],tg[4],tg[5]);
  }
  if (tid == 0) ncl = 0;

  // ---- hoisted independent loads: all in flight together (one latency) ----
  bool valid = (a < NA);
  float4 pb = pbox4[gid];              // pads: zero box (k0-initialized)
  float4 mt = meta4[gid];              // pads: z=-1
  unsigned long long m0=0, m1=0;
  if (valid){ m0 = mask[(size_t)gid*2]; m1 = mask[(size_t)gid*2+1]; }
  float bestv = __uint_as_float(obju[gid]);  // max_t iou*invm (k1-scattered)
  float olv   = obja[gid];
  float S0v   = S0a[gid];

  bool ib = valid && (mt.z > 0.0f);
  float px1=pb.x, py1=pb.y, px2=pb.z, py2=pb.w;
  int cnt = __popcll(m0) + __popcll(m1);

  __syncthreads();   // tb4/tcid/ncl ready

  // ---- compact conflicted anchors into cl[] (per-wave ballot + LDS base) ----
  bool myc = (cnt > 1);
  unsigned long long cb = __ballot(myc);
  int nb = __popcll(cb);
  int base = 0;
  if (lane == 0 && nb) base = atomicAdd(&ncl, nb);
  base = __shfl(base, 0);
  if (myc) cl[base + __popcll(cb & ((1ull << lane) - 1ull))] = tid;
  __syncthreads();

  // ---- worker pass: one WAVE per conflicted anchor, 2 targets per lane ----
  int tot = ncl;
  for (int ci = w; ci < tot; ci += 4){
    int aidx = cl[ci];
    int a2g  = b*256 + aidx;
    int gid2 = i*NAP + a2g;
    float4 pb2 = pbox4[gid2];          // uniform across wave (broadcast)
    float4 mt2 = meta4[gid2];
    bool ib2 = (mt2.z > 0.0f);
    float rc2 = fabsf(mt2.z);
    float Sg  = mt2.w;
    float sobj = use_d ? 0.0f : sobja[gid2];
    size_t pbase = (size_t)(i*NA + a2g)*PDIM;

    int ta = lane, tb = lane + 64;
    // both gathers issued before use -> one latency
    float dva = use_d ? D[(size_t)tcid[ta]*BAPC + gid2]
                      : dval_fn(sobj, pred[pbase + 5 + tcid[ta]]);
    float dvb = use_d ? D[(size_t)tcid[tb]*BAPC + gid2]
                      : dval_fn(sobj, pred[pbase + 5 + tcid[tb]]);

    float4 Ta = tb4[ta];
    float ioua = ib2 ? pair_iou(Ta.x,Ta.y,Ta.z,Ta.w,pb2.x,pb2.y,pb2.z,pb2.w) : 0.0f;
    bool inba = (mt2.x-Ta.x>0.0f)&&(mt2.y-Ta.y>0.0f)&&(Ta.z-mt2.x>0.0f)&&(Ta.w-mt2.y>0.0f);
    float txa=(Ta.x+Ta.z)*0.5f, tya=(Ta.y+Ta.w)*0.5f;
    bool inca = fmaxf(fabsf(mt2.x-txa),fabsf(mt2.y-tya)) < rc2;
    unsigned long long ka = key_of(cost_from(Sg, dva, ioua, inba&&inca, ib2), ta);

    float4 Tb = tb4[tb];
    float ioub = ib2 ? pair_iou(Tb.x,Tb.y,Tb.z,Tb.w,pb2.x,pb2.y,pb2.z,pb2.w) : 0.0f;
    bool inbb = (mt2.x-Tb.x>0.0f)&&(mt2.y-Tb.y>0.0f)&&(Tb.z-mt2.x>0.0f)&&(Tb.w-mt2.y>0.0f);
    float txb=(Tb.x+Tb.z)*0.5f, tyb=(Tb.y+Tb.w)*0.5f;
    bool incb = fmaxf(fabsf(mt2.x-txb),fabsf(mt2.y-tyb)) < rc2;
    unsigned long long kb = key_of(cost_from(Sg, dvb, ioub, inbb&&incb, ib2), tb);

    unsigned long long mn = (kb < ka) ? kb : ka;
    #pragma unroll
    for (int m = 1; m < 64; m <<= 1){
      unsigned long long o = __shfl_xor(mn, m);
      mn = (o < mn) ? o : mn;
    }
    if (lane == 0) bt_s[aidx] = (int)(mn & 0xFFFFFFFFull);
  }
  __syncthreads();

  // ---- epilogue: per-anchor losses (all data already in registers) ----
  float m=0.0f, vbox=0.0f, vobj=0.0f, vcls=0.0f;
  if (valid){
    float obj_t = ib ? fminf(fmaxf(bestv,0.0f),1.0f) : 0.0f;
    vobj = bce_fast(olv, obj_t);

    int tp = 0; bool mpv = false;
    if (cnt > 1){ tp = bt_s[tid]; mpv = true; }
    else if (cnt == 1){
      tp = m0 ? (__ffsll(m0)-1) : (64 + __ffsll(m1)-1);
      mpv = true;
    }

    if (mpv){
      m = 1.0f;
      float4 T = tb4[tp];
      float x1=T.x, y1=T.y, x2=T.z, y2=T.w;
      float w2 = fmaxf(fminf(px2,x2)-fmaxf(px1,x1),0.0f);
      float h2 = fmaxf(fminf(py2,y2)-fmaxf(py1,y1),0.0f);
      float inter = w2*h2;
      float wp=px2-px1, hp=py2-py1, wt=x2-x1, ht=y2-y1;
      float iou = inter/(wp*hp + wt*ht - inter + 1e-8f);
      float cw = fmaxf(px2,x2)-fminf(px1,x1);
      float ch = fmaxf(py2,y2)-fminf(py1,y1);
      float c2 = cw*cw + ch*ch + 1e-8f;
      float dx = (px1+px2)-(x1+x2), dy = (py1+py2)-(y1+y2);
      float rho2 = (dx*dx + dy*dy)/4.0f;
      float da = atanf(wt/(ht+1e-8f)) - atanf(wp/(hp+1e-8f));
      float v  = 0.4052847345693511f * da * da;   // 4/pi^2
      float alpha = v/(1.0f - iou + v + 1e-8f);
      vbox = 1.0f - (iou - rho2/c2 - alpha*v);

      int cc = tcid[tp];
      float xcc = pred[(size_t)(i*NA + a)*PDIM + 5 + cc];
      vcls = (S0v - xcc) * (1.0f/80.0f);   // sum_c bce(x_c, onehot) = S0 - x_cc
    }
  }

  // wave reduce -> LDS -> single atomic quad per BLOCK (528 vs 2112 quads)
  #pragma unroll
  for (int off=32; off>0; off>>=1){
    m    += __shfl_down(m, off);
    vbox += __shfl_down(vbox, off);
    vobj += __shfl_down(vobj, off);
    vcls += __shfl_down(vcls, off);
  }
  if (lane == 0) part[w] = make_float4(m, vbox, vobj, vcls);
  __syncthreads();
  if (tid == 0){
    float4 s0 = part[0], s1 = part[1], s2 = part[2], s3 = part[3];
    float4 s = make_float4(s0.x+s1.x+s2.x+s3.x, s0.y+s1.y+s2.y+s3.y,
                           s0.z+s1.z+s2.z+s3.z, s0.w+s1.w+s2.w+s3.w);
    int slot = (blockIdx.x & 63)*4;
    atomicAdd(&acc[slot+0], s.x);
    atomicAdd(&acc[slot+1], s.y);
    atomicAdd(&acc[slot+2], s.z);
    atomicAdd(&acc[slot+3], s.w);
  }
}

// ---------------- Kernel 3: finalize (reduce 64 accumulator slots) -----------
__global__ void k3_final(const float* __restrict__ acc, float* __restrict__ out){
  int l = threadIdx.x;   // 64 threads
  float4 v = ((const float4*)acc)[l];
  #pragma unroll
  for (int off=32; off>0; off>>=1){
    v.x += __shfl_down(v.x, off);
    v.y += __shfl_down(v.y, off);
    v.z += __shfl_down(v.z, off);
    v.w += __shfl_down(v.w, off);
  }
  if (l == 0){
    float n    = fmaxf(v.x, 1.0f);
    float lbox = 0.05f * v.y / n;
    float lobj = v.z / (float)(NB*NA);
    float lcls = 0.5f  * v.w / n;
    out[0] = lbox + lobj + lcls;
    out[1] = lbox; out[2] = lobj; out[3] = lcls;
  }
}

extern "C" void kernel_launch(void* const* d_in, const int* in_sizes, int n_in,
                              void* d_out, int out_size, void* d_ws, size_t ws_size,
                              hipStream_t stream) {
  const float* pred    = (const float*)d_in[0];
  const float* target  = (const float*)d_in[1];
  const float* grid    = (const float*)d_in[2];
  const float* stridev = (const float*)d_in[3];
  float* out = (float*)d_out;

  char* ws = (char*)d_ws;

  size_t off = 0;
  unsigned long long* mask = (unsigned long long*)(ws + off); off += BAPC*16;
  float* acc    = (float*)(ws + off); off += 64*4*4;
  float4* pbox4 = (float4*)(ws + off); off += BAPC*16;
  float4* meta4 = (float4*)(ws + off); off += BAPC*16;
  float* obja   = (float*)(ws + off); off += BAPC*4;
  float* sobja  = (float*)(ws + off); off += BAPC*4;
  float* S0a    = (float*)(ws + off); off += BAPC*4;
  unsigned int* obju = (unsigned int*)(ws + off); off += BAPC*4;
  float4* gaabb = (float4*)(ws + off); off += (size_t)NB*BPI*3*16;
  float* D      = (float*)(ws + off);
  const size_t need_d = off + (size_t)NCLS*BAPC*4;
  int use_d = (ws_size >= need_d) ? 1 : 0;

  // mask+acc+obju zeroed inside k0 (no memset dispatch)
  k0_precompute<<<NB*BPI, 256, 0, stream>>>(pred, target, grid, stridev,
                                            pbox4, meta4, obja, sobja, S0a, D, use_d,
                                            mask, obju, gaabb, acc);
  k1_pertarget <<<NB*NT,  256, 0, stream>>>(pbox4, meta4, D, use_d,
                                            sobja, pred, target, gaabb, obju, mask);
  k2_peranchor <<<NB*BPI2, 256, 0, stream>>>(pred, pbox4, meta4, obja, sobja, S0a,
                                             D, use_d, target, obju, mask, acc);
  k3_final     <<<1, 64, 0, stream>>>(acc, out);
}